// Round 9
// baseline (348.348 us; speedup 1.0000x reference)
//
#include <hip/hip_runtime.h>
#include <cstdint>
#include <cstddef>

#define TSEQ   2048
#define BATCH  2
#define BT     4096      // BATCH*TSEQ
#define DMODEL 1024
#define NHEADS 16
#define HDIM   64
#define FFDIM  4096
#define QKVS   3072      // row stride of fused qkv buffer

typedef __attribute__((ext_vector_type(8))) short short8;    // 8 bf16 = 4 VGPRs
typedef __attribute__((ext_vector_type(4))) short short4v;   // 8B of bf16
typedef __attribute__((ext_vector_type(4))) float floatx4;   // MFMA acc
typedef unsigned short us;

__device__ __forceinline__ float bf2f(us u) {
    union { unsigned int i; float f; } v; v.i = ((unsigned int)u) << 16; return v.f;
}
__device__ __forceinline__ us f2bf(float f) {
    union { float f; unsigned int i; } v; v.f = f;
    unsigned int r = v.i + 0x7fffu + ((v.i >> 16) & 1u);
    return (us)(r >> 16);
}
__device__ __forceinline__ unsigned int fbits(float f) {
    union { float f; unsigned int u; } v; v.f = f; return v.u;
}
// pack two f32 -> two bf16 (truncating; P in [0,1] so <=1 ULP down). lo -> low half.
__device__ __forceinline__ unsigned int pk_trunc(float lo, float hi) {
    return (fbits(hi) & 0xffff0000u) | (fbits(lo) >> 16);
}

// async global->LDS, 16B per lane. LDS dest = wave-uniform base + lane*16.
__device__ __forceinline__ void gld_lds16(const us* g, us* l) {
    __builtin_amdgcn_global_load_lds(
        (const __attribute__((address_space(1))) uint32_t*)(const void*)g,
        (__attribute__((address_space(3))) uint32_t*)(void*)l, 16, 0, 0);
}

// ============ prologue: 6 weight transposes + pre-norm fused into one launch =========
// blocks [0,12288): 32x32 transpose tiles (wq,wk,wv,wo: 4x1024 | w1: 4096 | w2: 4096)
// blocks [12288,16384): rmsnorm rows. All branches are block-uniform.
__global__ void prologue_k(const float* __restrict__ wq, const float* __restrict__ wk,
                           const float* __restrict__ wv, const float* __restrict__ wo,
                           const float* __restrict__ w1, const float* __restrict__ w2,
                           const float* __restrict__ x,  const float* __restrict__ w_pre,
                           us* __restrict__ wqkvt, us* __restrict__ wot,
                           us* __restrict__ w1t, us* __restrict__ w2t,
                           us* __restrict__ hb) {
    __shared__ us tile[32][33];
    __shared__ float red[4];
    int tb = blockIdx.x;
    int tx = threadIdx.x, ty = threadIdx.y;  // (32,8)
    if (tb >= 12288) {                        // ---- rmsnorm row ----
        int row = tb - 12288;
        int tid = ty * 32 + tx;
        float4 xv = *(const float4*)&x[(size_t)row * DMODEL + tid * 4];
        float f[4] = {xv.x, xv.y, xv.z, xv.w};
        float ss = 0.f;
        for (int e = 0; e < 4; ++e) ss += f[e] * f[e];
        for (int m = 1; m < 64; m <<= 1) ss += __shfl_xor(ss, m);
        if ((tid & 63) == 0) red[tid >> 6] = ss;
        __syncthreads();
        float tot = red[0] + red[1] + red[2] + red[3];
        float sc = rsqrtf(tot * (1.f / DMODEL) + 1e-6f);
        float4 wv4 = *(const float4*)&w_pre[tid * 4];
        float wf[4] = {wv4.x, wv4.y, wv4.z, wv4.w};
        us ol[4];
        for (int e = 0; e < 4; ++e) ol[e] = f2bf(f[e] * sc * wf[e]);
        *(uint2*)&hb[(size_t)row * DMODEL + tid * 4] = *(uint2*)ol;
        return;
    }
    const float* in; us* out; int K, N, nt, kt;
    if (tb < 4096) {
        int w = tb >> 10, u = tb & 1023;
        in = (w == 0) ? wq : (w == 1) ? wk : (w == 2) ? wv : wo;
        out = (w < 3) ? (wqkvt + (size_t)w * 1024 * 1024) : wot;
        K = 1024; N = 1024; nt = (u & 31) * 32; kt = (u >> 5) * 32;
    } else if (tb < 8192) {
        int u = tb - 4096;
        in = w1; out = w1t; K = 1024; N = 4096; nt = (u & 127) * 32; kt = (u >> 7) * 32;
    } else {
        int u = tb - 8192;
        in = w2; out = w2t; K = 4096; N = 1024; nt = (u & 31) * 32; kt = (u >> 5) * 32;
    }
    for (int i = 0; i < 4; ++i)
        tile[ty + 8 * i][tx] = f2bf(in[(size_t)(kt + ty + 8 * i) * N + nt + tx]);
    __syncthreads();
    for (int i = 0; i < 4; ++i)
        out[(size_t)(nt + ty + 8 * i) * K + kt + tx] = tile[tx][ty + 8 * i];
}

// ---------------- bf16 transpose: V (strided rows) -> Vt [B*D][T], key-permuted ---------
// Within each 64-key block, key k is stored at col sigma(k) = ((k&15)<<2)|((k&63)>>4).
// Matches the packed P storage in attn (storage col c holds key pi(c)=(c&3)*16+(c>>2);
// pi = sigma^-1), so the PV contraction sees identical key order on both operands.
__global__ void vtrans_k(const us* __restrict__ in, us* __restrict__ out, int istride) {
    __shared__ us tile[32][33];
    int b = blockIdx.z;
    int ct = blockIdx.x * 32;   // D tile
    int rt = blockIdx.y * 32;   // T tile
    int tx = threadIdx.x, ty = threadIdx.y; // (32,8)
    for (int i = 0; i < 4; ++i)
        tile[ty + 8 * i][tx] = in[((size_t)b * TSEQ + rt + ty + 8 * i) * istride + ct + tx];
    __syncthreads();
    int tt = rt + tx;
    int ts = (tt & ~63) | ((tt & 15) << 2) | ((tt & 63) >> 4);
    for (int i = 0; i < 4; ++i)
        out[((size_t)b * DMODEL + ct + ty + 8 * i) * TSEQ + ts] = tile[tx][ty + 8 * i];
}

// ---------------- Residual + RMSNorm: out = rmsnorm(a + b [+ b2]) * w ----------------
// NOTE: out may alias a (row-local) -> no __restrict__.
__global__ void resnorm_k(const us* a, const us* b,
                          const us* b2,
                          const float* w,
                          void* outp, int out_f32) {
    int row = blockIdx.x, t = threadIdx.x;
    us al[4], bl[4], cl[4];
    *(uint2*)al = *(const uint2*)&a[(size_t)row * DMODEL + t * 4];
    *(uint2*)bl = *(const uint2*)&b[(size_t)row * DMODEL + t * 4];
    if (b2) *(uint2*)cl = *(const uint2*)&b2[(size_t)row * DMODEL + t * 4];
    float f[4];
    float ss = 0.f;
    for (int e = 0; e < 4; ++e) {
        f[e] = bf2f(al[e]) + bf2f(bl[e]);
        if (b2) f[e] += bf2f(cl[e]);
        ss += f[e] * f[e];
    }
    for (int m = 1; m < 64; m <<= 1) ss += __shfl_xor(ss, m);
    __shared__ float red[4];
    if ((t & 63) == 0) red[t >> 6] = ss;
    __syncthreads();
    float tot = red[0] + red[1] + red[2] + red[3];
    float sc = rsqrtf(tot * (1.f / DMODEL) + 1e-6f);
    float4 wv = *(const float4*)&w[t * 4];
    float wf[4] = {wv.x, wv.y, wv.z, wv.w};
    if (out_f32) {
        float4 ov;
        ov.x = f[0] * sc * wf[0]; ov.y = f[1] * sc * wf[1];
        ov.z = f[2] * sc * wf[2]; ov.w = f[3] * sc * wf[3];
        *(float4*)&((float*)outp)[(size_t)row * DMODEL + t * 4] = ov;
    } else {
        us ol[4];
        for (int e = 0; e < 4; ++e) ol[e] = f2bf(f[e] * sc * wf[e]);
        *(uint2*)&((us*)outp)[(size_t)row * DMODEL + t * 4] = *(uint2*)ol;
    }
}

// ---------------- Residual + RMSNorm over 4 split-K partials (f32 out) ----------------
__global__ void resnorm4_k(const us* __restrict__ a, const us* __restrict__ p,
                           size_t pstride, const float* __restrict__ w,
                           float* __restrict__ out) {
    int row = blockIdx.x, t = threadIdx.x;
    size_t off = (size_t)row * DMODEL + t * 4;
    us al[4], pl[4][4];
    *(uint2*)al = *(const uint2*)&a[off];
#pragma unroll
    for (int z = 0; z < 4; ++z)
        *(uint2*)pl[z] = *(const uint2*)&p[off + z * pstride];
    float f[4];
    float ss = 0.f;
#pragma unroll
    for (int e = 0; e < 4; ++e) {
        f[e] = bf2f(al[e]) + bf2f(pl[0][e]) + bf2f(pl[1][e]) + bf2f(pl[2][e]) + bf2f(pl[3][e]);
        ss += f[e] * f[e];
    }
    for (int m = 1; m < 64; m <<= 1) ss += __shfl_xor(ss, m);
    __shared__ float red[4];
    if ((t & 63) == 0) red[t >> 6] = ss;
    __syncthreads();
    float tot = red[0] + red[1] + red[2] + red[3];
    float sc = rsqrtf(tot * (1.f / DMODEL) + 1e-6f);
    float4 wv = *(const float4*)&w[t * 4];
    float4 ov;
    ov.x = f[0] * sc * wv.x; ov.y = f[1] * sc * wv.y;
    ov.z = f[2] * sc * wv.z; ov.w = f[3] * sc * wv.w;
    *(float4*)&out[off] = ov;
}

// ---------------- legacy 128-tile 2-phase GEMM (kept for O-proj: short K, small) -------
template<int BN, int GX, bool SWZ>
__global__ __launch_bounds__(256, (BN == 256) ? 2 : 4)
void gemm_dbuf_k(const us* __restrict__ A,
                 const us* __restrict__ Bt,
                 us* __restrict__ C,
                 int M, int N, int K, int do_silu,
                 int Ks, size_t cstride) {
    constexpr int MI = 4, NI = BN / 32;
    constexpr int BDMA = BN / 64;
    __shared__ __align__(16) us As[2][128 * 32];
    __shared__ __align__(16) us Bs[2][BN * 32];
    int t = threadIdx.x;
    int n0 = blockIdx.x;
    int bx, by, z;
    if (SWZ) {
        int c = n0 & 7, bb = n0 >> 3;
        bx = bb % GX;
        int g = bb / GX;
        int yz = c + 8 * g;
        by = yz & 31; z = yz >> 5;
    } else {
        bx = n0 % GX;
        int bb = n0 / GX;
        by = bb & 31; z = bb >> 5;
    }
    int bm = by * 128, bn = bx * BN;
    int lane = t & 63, wave = t >> 6;
    int wm = (wave & 1) * 64, wn = (wave >> 1) * (BN / 2);
    int lr = lane & 15, lq = lane >> 4;

    int sr = lane >> 2;
    int sc = (((lane & 3) ^ ((lane >> 3) & 3)) * 8);
    const us* gA = A + (size_t)(bm + wave * 32 + sr) * K + sc + (size_t)z * Ks;
    const us* gB = Bt + (size_t)(bn + wave * (BN / 4) + sr) * K + sc + (size_t)z * Ks;
    const int aoff = (wave * 32) * 32;
    const int boff = (wave * (BN / 4)) * 32;
    C += (size_t)z * cstride;

    floatx4 acc[MI][NI];
#pragma unroll
    for (int mi = 0; mi < MI; ++mi)
#pragma unroll
        for (int ni = 0; ni < NI; ++ni)
            acc[mi][ni] = (floatx4){0.f, 0.f, 0.f, 0.f};

#pragma unroll
    for (int i = 0; i < 2; ++i)
        gld_lds16(gA + (size_t)(16 * i) * K, &As[0][aoff + i * 16 * 32]);
#pragma unroll
    for (int i = 0; i < BDMA; ++i)
        gld_lds16(gB + (size_t)(16 * i) * K, &Bs[0][boff + i * 16 * 32]);

    int aslot = ((lq ^ ((lr >> 1) & 3)) << 3);

    int nk = Ks >> 5;
    for (int kk = 0; kk < nk; ++kk) {
        __syncthreads();
        int cur = kk & 1, nxt = cur ^ 1;
        if (kk + 1 < nk) {
            size_t off = (size_t)(kk + 1) * 32;
#pragma unroll
            for (int i = 0; i < 2; ++i)
                gld_lds16(gA + (size_t)(16 * i) * K + off, &As[nxt][aoff + i * 16 * 32]);
#pragma unroll
            for (int i = 0; i < BDMA; ++i)
                gld_lds16(gB + (size_t)(16 * i) * K + off, &Bs[nxt][boff + i * 16 * 32]);
        }
        short8 a[MI], b[NI];
#pragma unroll
        for (int mi = 0; mi < MI; ++mi)
            a[mi] = *(const short8*)&As[cur][(wm + mi * 16 + lr) * 32 + aslot];
#pragma unroll
        for (int ni = 0; ni < NI; ++ni)
            b[ni] = *(const short8*)&Bs[cur][(wn + ni * 16 + lr) * 32 + aslot];
#pragma unroll
        for (int mi = 0; mi < MI; ++mi)
#pragma unroll
            for (int ni = 0; ni < NI; ++ni)
                acc[mi][ni] = __builtin_amdgcn_mfma_f32_16x16x32_bf16(a[mi], b[ni], acc[mi][ni], 0, 0, 0);
    }

#pragma unroll
    for (int mi = 0; mi < MI; ++mi)
#pragma unroll
        for (int ni = 0; ni < NI; ++ni)
#pragma unroll
            for (int r = 0; r < 4; ++r) {
                int m = bm + wm + mi * 16 + lq * 4 + r;
                int nn = bn + wn + ni * 16 + lr;
                float v = acc[mi][ni][r];
                if (do_silu) v = v / (1.f + __expf(-v));
                C[(size_t)m * N + nn] = f2bf(v);
            }
}

// ================= R21: 128x256 GEMM, BK=32, 48 KiB LDS -> 2-3 blocks/CU =================
// Evidence: 5 schedule variants all pinned at 44-49.5us with every pipe ~30% busy at
// 1 block/CU (2 waves/SIMD) -> stall-bound, and register pressure forbids in-wave
// pipelining at 256^2. Fix: smaller tile so grids reach 2/CU (16 waves/CU) WITHOUT
// split-K combine passes: FFN1 32x16=512 blk, QKV 32x12=384, FFN2 sk4=512.
// Per wave: C 64x64 (acc 4x4), 8 ds_read_b128 + 16 MFMA + 3 gld per K-tile(32), R20's
// 1-barrier schedule. Swizzle algebra identical to R20 at 4-chunk granularity:
// stage source chunk = (lane&3)^(row&3), read slot = lq^(row&3) -> returns chunk lq.

#define BAR8 __builtin_amdgcn_s_barrier()
#define SB0  __builtin_amdgcn_sched_barrier(0)
#define VM0 do { asm volatile("s_waitcnt vmcnt(0)" ::: "memory"); } while (0)

template<int GXc>
__global__ __launch_bounds__(512, 2)
void gemm128_k(const us* __restrict__ A, const us* __restrict__ Bt, us* __restrict__ C,
               int N, int K, int Ks, int do_silu, size_t cstride) {
    __shared__ __align__(16) us Al[2][128 * 32];   // 2 x 8 KiB
    __shared__ __align__(16) us Bl[2][256 * 32];   // 2 x 16 KiB
    int t = threadIdx.x, lane = t & 63, wave = t >> 6;
    int n0 = blockIdx.x;
    int by = n0 & 31, rest = n0 >> 5;       // M=4096 -> 32 row-blocks of 128
    int bx = rest % GXc, z = rest / GXc;
    int bm = by * 128, bn = bx * 256;
    int lr = lane & 15, lq = lane >> 4;     // lq in 0..3
    int wm2 = wave >> 2, wn2 = wave & 3;    // 2M x 4N wave grid, per-wave C 64x64

    // staging: rows of 32 elems (64 B); gld covers 16 rows (lane>>2), 4 chunks (lane&3)
    int srow = lane >> 2;
    int schk = ((lane & 3) ^ (srow & 3)) * 8;   // pre-swizzled source chunk
    const us* ga = A + (size_t)(bm + wave * 16 + srow) * K + schk + (size_t)z * Ks;
    const us* gb = Bt + (size_t)(bn + wave * 32 + srow) * K + schk + (size_t)z * Ks;
    const size_t r16 = (size_t)16 * K;
    us* dA0 = &Al[0][wave * 512];  us* dA1 = &Al[1][wave * 512];
    us* dB0 = &Bl[0][wave * 1024]; us* dB1 = &Bl[1][wave * 1024];
    C += (size_t)z * cstride;

    // read bases: row = (wm2|wn2)*64 + frag*16 + lr; slot = lq ^ (row&3), row&3 == lr&3
    const int rsw = (lq ^ (lr & 3)) * 8;
    const us* pa0 = &Al[0][(wm2 * 64 + lr) * 32 + rsw];
    const us* pa1 = &Al[1][(wm2 * 64 + lr) * 32 + rsw];
    const us* pb0 = &Bl[0][(wn2 * 64 + lr) * 32 + rsw];
    const us* pb1 = &Bl[1][(wn2 * 64 + lr) * 32 + rsw];

#define STG(d) do { \
    gld_lds16(ga, dA##d); \
    gld_lds16(gb, dB##d); gld_lds16(gb + r16, dB##d + 512); \
    ga += 32; gb += 32; } while (0)
#define RD(D) do { \
    aF[0] = *(const short8*)(pa##D);        aF[1] = *(const short8*)(pa##D + 512); \
    aF[2] = *(const short8*)(pa##D + 1024); aF[3] = *(const short8*)(pa##D + 1536); \
    bF[0] = *(const short8*)(pb##D);        bF[1] = *(const short8*)(pb##D + 512); \
    bF[2] = *(const short8*)(pb##D + 1024); bF[3] = *(const short8*)(pb##D + 1536); } while (0)
#define MM16 do { \
    _Pragma("unroll") \
    for (int mf = 0; mf < 4; ++mf) { \
        acc[mf][0] = __builtin_amdgcn_mfma_f32_16x16x32_bf16(aF[mf], bF[0], acc[mf][0], 0, 0, 0); \
        acc[mf][1] = __builtin_amdgcn_mfma_f32_16x16x32_bf16(aF[mf], bF[1], acc[mf][1], 0, 0, 0); \
        acc[mf][2] = __builtin_amdgcn_mfma_f32_16x16x32_bf16(aF[mf], bF[2], acc[mf][2], 0, 0, 0); \
        acc[mf][3] = __builtin_amdgcn_mfma_f32_16x16x32_bf16(aF[mf], bF[3], acc[mf][3], 0, 0, 0); \
    } } while (0)
#define TILE_S(D, E) do { \
    BAR8; \
    RD(D); \
    SB0; STG(E); SB0; \
    __builtin_amdgcn_s_setprio(1); MM16; __builtin_amdgcn_s_setprio(0); \
    VM0; } while (0)
#define TILE_N(D) do { \
    BAR8; \
    RD(D); \
    __builtin_amdgcn_s_setprio(1); MM16; __builtin_amdgcn_s_setprio(0); } while (0)

    floatx4 acc[4][4];
#pragma unroll
    for (int mf = 0; mf < 4; ++mf)
#pragma unroll
        for (int nf = 0; nf < 4; ++nf)
            acc[mf][nf] = (floatx4){0.f, 0.f, 0.f, 0.f};

    short8 aF[4], bF[4];

    // prologue: stage tile0 -> buf0, drain once
    STG(0);
    VM0;

    const int NT = Ks >> 5;                 // K-tiles of 32; Ks=1024 -> 32
    for (int i = 0; i < NT / 2 - 1; ++i) {
        TILE_S(0, 1);
        TILE_S(1, 0);
    }
    TILE_S(0, 1);
    TILE_N(1);

    // epilogue: C/D layout col = lane&15, row = (lane>>4)*4 + r
    int cm = bm + wm2 * 64, cn = bn + wn2 * 64;
#pragma unroll
    for (int mf = 0; mf < 4; ++mf)
#pragma unroll
        for (int nf = 0; nf < 4; ++nf)
#pragma unroll
            for (int r = 0; r < 4; ++r) {
                int m = cm + mf * 16 + lq * 4 + r;
                int nn = cn + nf * 16 + lr;
                float v = acc[mf][nf][r];
                if (do_silu) v = v / (1.f + __expf(-v));
                C[(size_t)m * N + nn] = f2bf(v);
            }
#undef STG
#undef RD
#undef MM16
#undef TILE_S
#undef TILE_N
}

// ================= Flash attention: 512-thread blocks, 2 q-tiles sharing one K/V pass ======
// R17: P materialized via truncating bit-pack + ds_write_b64 (short4v, same TBAA class as
// the short8 reload) + explicit lgkmcnt(0)+sched_barrier fence before the PV reads.
// P storage col c holds key pi(c)=(c&3)*16+(c>>2); V is pre-permuted by sigma=pi^-1
// in vtrans_k so PV k-slots line up.
#define PSTR 72

template<bool DIAG>
__device__ __forceinline__ void flash_tile_nm(
    const short8& qf0, const short8& qf1,
    floatx4* oa, float* lrw,
    const us* Ks, const us* Vts, us* Ps, const short8& ones,
    int lr, int lq, int sub)
{
    floatx4 s[4];
#pragma unroll
    for (int n = 0; n < 4; ++n) {
        int R = n * 16 + lr;
        short8 kf0 = *(const short8*)&Ks[R * 64 + ((lq ^ (R & 7)) << 3)];
        short8 kf1 = *(const short8*)&Ks[R * 64 + (((lq + 4) ^ (R & 7)) << 3)];
        floatx4 z = (floatx4){0.f, 0.f, 0.f, 0.f};
        z = __builtin_amdgcn_mfma_f32_16x16x32_bf16(qf0, kf0, z, 0, 0, 0);
        s[n] = __builtin_amdgcn_mfma_f32_16x16x32_bf16(qf1, kf1, z, 0, 0, 0);
    }
    if (DIAG) {
#pragma unroll
        for (int n = 0; n < 4; ++n)
#pragma unroll
            for (int r = 0; r < 4; ++r)
                if ((n * 16 + lr) > (sub * 16 + lq * 4 + r)) s[n][r] = -1e30f;  // exp2 -> 0
    }
    // packed P write: keys {n*16+lr} -> storage cols lr*4+n (pi-permuted layout)
#pragma unroll
    for (int r = 0; r < 4; ++r) {
        union { unsigned int u[2]; short4v v; } pk;
        pk.u[0] = pk_trunc(__builtin_amdgcn_exp2f(s[0][r]), __builtin_amdgcn_exp2f(s[1][r]));
        pk.u[1] = pk_trunc(__builtin_amdgcn_exp2f(s[2][r]), __builtin_amdgcn_exp2f(s[3][r]));
        *(short4v*)&Ps[(lq * 4 + r) * PSTR + lr * 4] = pk.v;
    }
    // ensure the 4 ds_write_b64 above complete before the same wave's ds_reads below
    asm volatile("s_waitcnt lgkmcnt(0)" ::: "memory");
    __builtin_amdgcn_sched_barrier(0);

    floatx4 zs = (floatx4){0.f, 0.f, 0.f, 0.f};
    __builtin_amdgcn_s_setprio(1);
#pragma unroll
    for (int kx = 0; kx < 2; ++kx) {
        short8 pf = *(const short8*)&Ps[lr * PSTR + kx * 32 + lq * 8];
        zs = __builtin_amdgcn_mfma_f32_16x16x32_bf16(pf, ones, zs, 0, 0, 0);
#pragma unroll
        for (int nd = 0; nd < 4; ++nd) {
            int R = nd * 16 + lr;
            short8 vf = *(const short8*)&Vts[R * 64 + ((((kx << 2) | lq) ^ (R & 7)) << 3)];
            oa[nd] = __builtin_amdgcn_mfma_f32_16x16x32_bf16(pf, vf, oa[nd], 0, 0, 0);
        }
    }
    __builtin_amdgcn_s_setprio(0);
#pragma unroll
    for (int r = 0; r < 4; ++r) lrw[r] += zs[r];
}

__global__ __launch_bounds__(512, 6) void attn_k(const us* __restrict__ q,
                                                 const us* __restrict__ kg,
                                                 const us* __restrict__ vt,
                                                 us* __restrict__ o,
                                                 us* __restrict__ Po,
                                                 float* __restrict__ Pl) {
    __shared__ __align__(16) us Ks[2][64 * 64];
    __shared__ __align__(16) us Vts[2][64 * 64];
    __shared__ __align__(16) us Ps[8 * 16 * PSTR];
    int j = blockIdx.x;
    int part = (j >= 16);
    int P = part ? (j - 8) : j;
    int qtA = 2 * P, qtB = 2 * P + 1;
    int k0 = part ? 16 : 0;
    int k1 = part ? qtB : (qtB < 15 ? qtB : 15);
    bool fin = (!part) && (P < 8);
    int bh = blockIdx.y;
    int b = bh >> 4, h = bh & 15;
    size_t base = (size_t)b * TSEQ;
    const us* vth = vt + ((size_t)b * DMODEL + h * 64) * TSEQ;
    int t = threadIdx.x, lane = t & 63, wave = t >> 6;   // wave 0..7
    int sub = wave & 3, grp = wave >> 2;                 // strip index, q-tile group
    int myqt = grp ? qtB : qtA;
    int lr = lane & 15, lq = lane >> 4;

    const float SC = 0.18033688011112042f;  // (1/8)*log2(e)
    int qrow = myqt * 64 + sub * 16 + lr;
    short8 qf0 = *(const short8*)&q[(base + qrow) * QKVS + h * 64 + lq * 8];
    short8 qf1 = *(const short8*)&q[(base + qrow) * QKVS + h * 64 + 32 + lq * 8];
#pragma unroll
    for (int e = 0; e < 8; ++e) {
        qf0[e] = (short)f2bf(bf2f((us)qf0[e]) * SC);
        qf1[e] = (short)f2bf(bf2f((us)qf1[e]) * SC);
    }
    short8 ones;
#pragma unroll
    for (int e = 0; e < 8; ++e) ones[e] = (short)0x3F80;  // bf16 1.0

    us* Psw = &Ps[wave * 16 * PSTR];

    floatx4 oa[4];
    float lrw[4] = {0.f, 0.f, 0.f, 0.f};
#pragma unroll
    for (int i = 0; i < 4; ++i) oa[i] = (floatx4){0.f, 0.f, 0.f, 0.f};

    int rsub = lane >> 3;
    int cda = ((lane & 7) ^ rsub) * 8;
    const us* gK = kg + (base + wave * 8 + rsub) * QKVS + h * 64 + cda;
    const us* gV = vth + (size_t)(wave * 8 + rsub) * TSEQ + cda;

    gld_lds16(gK + (size_t)(k0 * 64) * QKVS, &Ks[0][(wave * 8) * 64]);
    gld_lds16(gV + k0 * 64, &Vts[0][(wave * 8) * 64]);

    for (int kt = k0; kt <= k1; ++kt) {
        __syncthreads();
        int cur = (kt - k0) & 1, nxt = cur ^ 1;
        if (kt < k1) {
            gld_lds16(gK + (size_t)((kt + 1) * 64) * QKVS, &Ks[nxt][(wave * 8) * 64]);
            gld_lds16(gV + (kt + 1) * 64, &Vts[nxt][(wave * 8) * 64]);
        }
        if (kt <= myqt) {
            if (kt == myqt)
                flash_tile_nm<true>(qf0, qf1, oa, lrw, Ks[cur], Vts[cur], Psw, ones, lr, lq, sub);
            else
                flash_tile_nm<false>(qf0, qf1, oa, lrw, Ks[cur], Vts[cur], Psw, ones, lr, lq, sub);
        }
    }

    if (fin) {
#pragma unroll
        for (int nd = 0; nd < 4; ++nd)
#pragma unroll
            for (int r = 0; r < 4; ++r) {
                int tok = myqt * 64 + sub * 16 + lq * 4 + r;
                o[(base + tok) * DMODEL + h * 64 + nd * 16 + lr] = f2bf(oa[nd][r] / lrw[r]);
            }
    } else {
#pragma unroll
        for (int nd = 0; nd < 4; ++nd)
#pragma unroll
            for (int r = 0; r < 4; ++r) {
                int tok = myqt * 64 + sub * 16 + lq * 4 + r;
                size_t pb = ((size_t)(part * BATCH + b) * 1024 + (tok - 1024)) * 1024;
                Po[pb + h * 64 + nd * 16 + lr] = f2bf(oa[nd][r]);
            }
        if (lr == 0) {
#pragma unroll
            for (int r = 0; r < 4; ++r) {
                int tok = myqt * 64 + sub * 16 + lq * 4 + r;
                Pl[((part * BATCH + b) * NHEADS + h) * TSEQ + tok] = lrw[r];
            }
        }
    }
}

__global__ void merge_k(const us* __restrict__ Po, const float* __restrict__ Pl,
                        us* __restrict__ ab) {
    int row = blockIdx.x;            // 0..2047
    int b = row >> 10, tloc = row & 1023;
    int t = 1024 + tloc;
    int t4 = threadIdx.x * 4;
    int h = t4 >> 6;
    float l0 = Pl[((0 * BATCH + b) * NHEADS + h) * TSEQ + t];
    float l1 = Pl[((1 * BATCH + b) * NHEADS + h) * TSEQ + t];
    float inv = 1.f / (l0 + l1);
    size_t o0 = ((size_t)(0 * BATCH + b) * 1024 + tloc) * 1024 + t4;
    size_t o1 = ((size_t)(1 * BATCH + b) * 1024 + tloc) * 1024 + t4;
    us p0[4], p1[4], ol[4];
    *(uint2*)p0 = *(const uint2*)&Po[o0];
    *(uint2*)p1 = *(const uint2*)&Po[o1];
    for (int e = 0; e < 4; ++e)
        ol[e] = f2bf((bf2f(p0[e]) + bf2f(p1[e])) * inv);
    *(uint2*)&ab[((size_t)b * TSEQ + t) * DMODEL + t4] = *(uint2*)ol;
}

// ---------------- launch ----------------
extern "C" void kernel_launch(void* const* d_in, const int* in_sizes, int n_in,
                              void* d_out, int out_size, void* d_ws, size_t ws_size,
                              hipStream_t stream) {
    const float* x      = (const float*)d_in[0];
    const float* w_pre  = (const float*)d_in[1];
    const float* wq     = (const float*)d_in[2];
    const float* wk     = (const float*)d_in[3];
    const float* wv     = (const float*)d_in[4];
    const float* wo     = (const float*)d_in[5];
    const float* w_attn = (const float*)d_in[6];
    const float* w1     = (const float*)d_in[7];
    const float* w2     = (const float*)d_in[8];
    const float* w_ffn  = (const float*)d_in[9];

    char* ws = (char*)d_ws;
    const size_t MB = 1024 * 1024;
    us* hb    = (us*)(ws + 0);
    us* qkvb  = (us*)(ws + 8 * MB);
    us* ab    = (us*)(ws + 32 * MB);
    us* vtb   = (us*)(ws + 40 * MB);
    us* ob0   = (us*)(ws + 40 * MB);
    us* ob1   = (us*)(ws + 48 * MB);
    us* Pob   = (us*)(ws + 48 * MB);
    us* yb    = (us*)(ws + 0);        // in-place over hb (row-local safe)
    us* wqkvt = (us*)(ws + 56 * MB);  // 6 MB
    us* wot   = (us*)(ws + 62 * MB);  // 2 MB
    us* w1t   = (us*)(ws + 64 * MB);  // 8 MB
    us* w2t   = (us*)(ws + 72 * MB);  // 8 MB
    float* Pl = (float*)(ws + 80 * MB); // 1 MB
    us* midb  = (us*)(ws + 8 * MB);   // 32 MB FFN mid (qkvb+ab dead)
    us* fb0   = (us*)(ws + 40 * MB);  // FFN2 split-K=4 partials, 8 MB stride, [40,72)
    const size_t FB_STR = (8 * MB) / 2;

    dim3 tb(32, 8);
    // 6 transposes + pre-norm in one launch (12288 tiles + 4096 rows)
    prologue_k<<<dim3(16384), tb, 0, stream>>>(
        wq, wk, wv, wo, w1, w2, x, w_pre, wqkvt, wot, w1t, w2t, hb);

    // fused QKV: R21 128x256 BK=32, 32x12 = 384 blocks (1.5/CU)
    gemm128_k<12><<<dim3(384), 512, 0, stream>>>(
        hb, wqkvt, qkvb, QKVS, DMODEL, DMODEL, 0, 0);

    vtrans_k<<<dim3(DMODEL / 32, TSEQ / 32, BATCH), tb, 0, stream>>>(qkvb + 2048, vtb, QKVS);

    attn_k<<<dim3(24, BATCH * NHEADS), 512, 0, stream>>>(qkvb, qkvb + 1024, vtb, ab, Pob, Pl);
    merge_k<<<dim3(BATCH * 1024), 256, 0, stream>>>(Pob, Pl, ab);

    // O-proj: legacy 2-phase, GX=8, split-K=2 -> 512 blocks (short K; small op)
    gemm_dbuf_k<128, 8, true><<<dim3(512), 256, 0, stream>>>(
        ab, wot, ob0, BT, DMODEL, DMODEL, 0, DMODEL / 2, (size_t)BT * DMODEL);
    resnorm_k<<<BT, 256, 0, stream>>>(hb, ob0, ob1, w_attn, yb, 0);

    // FFN1: R21 128x256, 32x16 = 512 blocks (2/CU), fused silu, NO split-K
    gemm128_k<16><<<dim3(512), 512, 0, stream>>>(
        yb, w1t, midb, FFDIM, DMODEL, DMODEL, 1, 0);
    // FFN2: R21 128x256, split-K=4 -> 32x4x4 = 512 blocks (2/CU), Ks=1024
    gemm128_k<4><<<dim3(512), 512, 0, stream>>>(
        midb, w2t, fb0, DMODEL, FFDIM, FFDIM / 4, 0, FB_STR);
    resnorm4_k<<<BT, 256, 0, stream>>>(yb, fb0, FB_STR, w_ffn, (float*)d_out);
}

// Round 10
// 322.389 us; speedup vs baseline: 1.0805x; 1.0805x over previous
//
#include <hip/hip_runtime.h>
#include <cstdint>
#include <cstddef>

#define TSEQ   2048
#define BATCH  2
#define BT     4096      // BATCH*TSEQ
#define DMODEL 1024
#define NHEADS 16
#define HDIM   64
#define FFDIM  4096
#define QKVS   3072      // row stride of fused qkv buffer

typedef __attribute__((ext_vector_type(8))) short short8;    // 8 bf16 = 4 VGPRs
typedef __attribute__((ext_vector_type(4))) short short4v;   // 8B of bf16
typedef __attribute__((ext_vector_type(4))) float floatx4;   // MFMA acc
typedef unsigned short us;

__device__ __forceinline__ float bf2f(us u) {
    union { unsigned int i; float f; } v; v.i = ((unsigned int)u) << 16; return v.f;
}
__device__ __forceinline__ us f2bf(float f) {
    union { float f; unsigned int i; } v; v.f = f;
    unsigned int r = v.i + 0x7fffu + ((v.i >> 16) & 1u);
    return (us)(r >> 16);
}
__device__ __forceinline__ unsigned int fbits(float f) {
    union { float f; unsigned int u; } v; v.f = f; return v.u;
}
// pack two f32 -> two bf16 (truncating; P in [0,1] so <=1 ULP down). lo -> low half.
__device__ __forceinline__ unsigned int pk_trunc(float lo, float hi) {
    return (fbits(hi) & 0xffff0000u) | (fbits(lo) >> 16);
}

// async global->LDS, 16B per lane. LDS dest = wave-uniform base + lane*16.
__device__ __forceinline__ void gld_lds16(const us* g, us* l) {
    __builtin_amdgcn_global_load_lds(
        (const __attribute__((address_space(1))) uint32_t*)(const void*)g,
        (__attribute__((address_space(3))) uint32_t*)(void*)l, 16, 0, 0);
}

// ============ prologue: 6 weight transposes + pre-norm fused into one launch =========
__global__ void prologue_k(const float* __restrict__ wq, const float* __restrict__ wk,
                           const float* __restrict__ wv, const float* __restrict__ wo,
                           const float* __restrict__ w1, const float* __restrict__ w2,
                           const float* __restrict__ x,  const float* __restrict__ w_pre,
                           us* __restrict__ wqkvt, us* __restrict__ wot,
                           us* __restrict__ w1t, us* __restrict__ w2t,
                           us* __restrict__ hb) {
    __shared__ us tile[32][33];
    __shared__ float red[4];
    int tb = blockIdx.x;
    int tx = threadIdx.x, ty = threadIdx.y;  // (32,8)
    if (tb >= 12288) {                        // ---- rmsnorm row ----
        int row = tb - 12288;
        int tid = ty * 32 + tx;
        float4 xv = *(const float4*)&x[(size_t)row * DMODEL + tid * 4];
        float f[4] = {xv.x, xv.y, xv.z, xv.w};
        float ss = 0.f;
        for (int e = 0; e < 4; ++e) ss += f[e] * f[e];
        for (int m = 1; m < 64; m <<= 1) ss += __shfl_xor(ss, m);
        if ((tid & 63) == 0) red[tid >> 6] = ss;
        __syncthreads();
        float tot = red[0] + red[1] + red[2] + red[3];
        float sc = rsqrtf(tot * (1.f / DMODEL) + 1e-6f);
        float4 wv4 = *(const float4*)&w_pre[tid * 4];
        float wf[4] = {wv4.x, wv4.y, wv4.z, wv4.w};
        us ol[4];
        for (int e = 0; e < 4; ++e) ol[e] = f2bf(f[e] * sc * wf[e]);
        *(uint2*)&hb[(size_t)row * DMODEL + tid * 4] = *(uint2*)ol;
        return;
    }
    const float* in; us* out; int K, N, nt, kt;
    if (tb < 4096) {
        int w = tb >> 10, u = tb & 1023;
        in = (w == 0) ? wq : (w == 1) ? wk : (w == 2) ? wv : wo;
        out = (w < 3) ? (wqkvt + (size_t)w * 1024 * 1024) : wot;
        K = 1024; N = 1024; nt = (u & 31) * 32; kt = (u >> 5) * 32;
    } else if (tb < 8192) {
        int u = tb - 4096;
        in = w1; out = w1t; K = 1024; N = 4096; nt = (u & 127) * 32; kt = (u >> 7) * 32;
    } else {
        int u = tb - 8192;
        in = w2; out = w2t; K = 4096; N = 1024; nt = (u & 31) * 32; kt = (u >> 5) * 32;
    }
    for (int i = 0; i < 4; ++i)
        tile[ty + 8 * i][tx] = f2bf(in[(size_t)(kt + ty + 8 * i) * N + nt + tx]);
    __syncthreads();
    for (int i = 0; i < 4; ++i)
        out[(size_t)(nt + ty + 8 * i) * K + kt + tx] = tile[tx][ty + 8 * i];
}

// ---------------- bf16 transpose: V (strided rows) -> Vt [B*D][T], key-permuted ---------
__global__ void vtrans_k(const us* __restrict__ in, us* __restrict__ out, int istride) {
    __shared__ us tile[32][33];
    int b = blockIdx.z;
    int ct = blockIdx.x * 32;   // D tile
    int rt = blockIdx.y * 32;   // T tile
    int tx = threadIdx.x, ty = threadIdx.y; // (32,8)
    for (int i = 0; i < 4; ++i)
        tile[ty + 8 * i][tx] = in[((size_t)b * TSEQ + rt + ty + 8 * i) * istride + ct + tx];
    __syncthreads();
    int tt = rt + tx;
    int ts = (tt & ~63) | ((tt & 15) << 2) | ((tt & 63) >> 4);
    for (int i = 0; i < 4; ++i)
        out[((size_t)b * DMODEL + ct + ty + 8 * i) * TSEQ + ts] = tile[tx][ty + 8 * i];
}

// ---------------- Residual + RMSNorm: out = rmsnorm(a + b [+ b2]) * w ----------------
__global__ void resnorm_k(const us* a, const us* b,
                          const us* b2,
                          const float* w,
                          void* outp, int out_f32) {
    int row = blockIdx.x, t = threadIdx.x;
    us al[4], bl[4], cl[4];
    *(uint2*)al = *(const uint2*)&a[(size_t)row * DMODEL + t * 4];
    *(uint2*)bl = *(const uint2*)&b[(size_t)row * DMODEL + t * 4];
    if (b2) *(uint2*)cl = *(const uint2*)&b2[(size_t)row * DMODEL + t * 4];
    float f[4];
    float ss = 0.f;
    for (int e = 0; e < 4; ++e) {
        f[e] = bf2f(al[e]) + bf2f(bl[e]);
        if (b2) f[e] += bf2f(cl[e]);
        ss += f[e] * f[e];
    }
    for (int m = 1; m < 64; m <<= 1) ss += __shfl_xor(ss, m);
    __shared__ float red[4];
    if ((t & 63) == 0) red[t >> 6] = ss;
    __syncthreads();
    float tot = red[0] + red[1] + red[2] + red[3];
    float sc = rsqrtf(tot * (1.f / DMODEL) + 1e-6f);
    float4 wv = *(const float4*)&w[t * 4];
    float wf[4] = {wv.x, wv.y, wv.z, wv.w};
    if (out_f32) {
        float4 ov;
        ov.x = f[0] * sc * wf[0]; ov.y = f[1] * sc * wf[1];
        ov.z = f[2] * sc * wf[2]; ov.w = f[3] * sc * wf[3];
        *(float4*)&((float*)outp)[(size_t)row * DMODEL + t * 4] = ov;
    } else {
        us ol[4];
        for (int e = 0; e < 4; ++e) ol[e] = f2bf(f[e] * sc * wf[e]);
        *(uint2*)&((us*)outp)[(size_t)row * DMODEL + t * 4] = *(uint2*)ol;
    }
}

// ---------------- Residual + RMSNorm over 4 split-K partials (f32 out) ----------------
__global__ void resnorm4_k(const us* __restrict__ a, const us* __restrict__ p,
                           size_t pstride, const float* __restrict__ w,
                           float* __restrict__ out) {
    int row = blockIdx.x, t = threadIdx.x;
    size_t off = (size_t)row * DMODEL + t * 4;
    us al[4], pl[4][4];
    *(uint2*)al = *(const uint2*)&a[off];
#pragma unroll
    for (int z = 0; z < 4; ++z)
        *(uint2*)pl[z] = *(const uint2*)&p[off + z * pstride];
    float f[4];
    float ss = 0.f;
#pragma unroll
    for (int e = 0; e < 4; ++e) {
        f[e] = bf2f(al[e]) + bf2f(pl[0][e]) + bf2f(pl[1][e]) + bf2f(pl[2][e]) + bf2f(pl[3][e]);
        ss += f[e] * f[e];
    }
    for (int m = 1; m < 64; m <<= 1) ss += __shfl_xor(ss, m);
    __shared__ float red[4];
    if ((t & 63) == 0) red[t >> 6] = ss;
    __syncthreads();
    float tot = red[0] + red[1] + red[2] + red[3];
    float sc = rsqrtf(tot * (1.f / DMODEL) + 1e-6f);
    float4 wv = *(const float4*)&w[t * 4];
    float4 ov;
    ov.x = f[0] * sc * wv.x; ov.y = f[1] * sc * wv.y;
    ov.z = f[2] * sc * wv.z; ov.w = f[3] * sc * wv.w;
    *(float4*)&out[off] = ov;
}

// ---------------- legacy 128-tile 2-phase GEMM (kept for O-proj: short K, small) -------
template<int BN, int GX, bool SWZ>
__global__ __launch_bounds__(256, (BN == 256) ? 2 : 4)
void gemm_dbuf_k(const us* __restrict__ A,
                 const us* __restrict__ Bt,
                 us* __restrict__ C,
                 int M, int N, int K, int do_silu,
                 int Ks, size_t cstride) {
    constexpr int MI = 4, NI = BN / 32;
    constexpr int BDMA = BN / 64;
    __shared__ __align__(16) us As[2][128 * 32];
    __shared__ __align__(16) us Bs[2][BN * 32];
    int t = threadIdx.x;
    int n0 = blockIdx.x;
    int bx, by, z;
    if (SWZ) {
        int c = n0 & 7, bb = n0 >> 3;
        bx = bb % GX;
        int g = bb / GX;
        int yz = c + 8 * g;
        by = yz & 31; z = yz >> 5;
    } else {
        bx = n0 % GX;
        int bb = n0 / GX;
        by = bb & 31; z = bb >> 5;
    }
    int bm = by * 128, bn = bx * BN;
    int lane = t & 63, wave = t >> 6;
    int wm = (wave & 1) * 64, wn = (wave >> 1) * (BN / 2);
    int lr = lane & 15, lq = lane >> 4;

    int sr = lane >> 2;
    int sc = (((lane & 3) ^ ((lane >> 3) & 3)) * 8);
    const us* gA = A + (size_t)(bm + wave * 32 + sr) * K + sc + (size_t)z * Ks;
    const us* gB = Bt + (size_t)(bn + wave * (BN / 4) + sr) * K + sc + (size_t)z * Ks;
    const int aoff = (wave * 32) * 32;
    const int boff = (wave * (BN / 4)) * 32;
    C += (size_t)z * cstride;

    floatx4 acc[MI][NI];
#pragma unroll
    for (int mi = 0; mi < MI; ++mi)
#pragma unroll
        for (int ni = 0; ni < NI; ++ni)
            acc[mi][ni] = (floatx4){0.f, 0.f, 0.f, 0.f};

#pragma unroll
    for (int i = 0; i < 2; ++i)
        gld_lds16(gA + (size_t)(16 * i) * K, &As[0][aoff + i * 16 * 32]);
#pragma unroll
    for (int i = 0; i < BDMA; ++i)
        gld_lds16(gB + (size_t)(16 * i) * K, &Bs[0][boff + i * 16 * 32]);

    int aslot = ((lq ^ ((lr >> 1) & 3)) << 3);

    int nk = Ks >> 5;
    for (int kk = 0; kk < nk; ++kk) {
        __syncthreads();
        int cur = kk & 1, nxt = cur ^ 1;
        if (kk + 1 < nk) {
            size_t off = (size_t)(kk + 1) * 32;
#pragma unroll
            for (int i = 0; i < 2; ++i)
                gld_lds16(gA + (size_t)(16 * i) * K + off, &As[nxt][aoff + i * 16 * 32]);
#pragma unroll
            for (int i = 0; i < BDMA; ++i)
                gld_lds16(gB + (size_t)(16 * i) * K + off, &Bs[nxt][boff + i * 16 * 32]);
        }
        short8 a[MI], b[NI];
#pragma unroll
        for (int mi = 0; mi < MI; ++mi)
            a[mi] = *(const short8*)&As[cur][(wm + mi * 16 + lr) * 32 + aslot];
#pragma unroll
        for (int ni = 0; ni < NI; ++ni)
            b[ni] = *(const short8*)&Bs[cur][(wn + ni * 16 + lr) * 32 + aslot];
#pragma unroll
        for (int mi = 0; mi < MI; ++mi)
#pragma unroll
            for (int ni = 0; ni < NI; ++ni)
                acc[mi][ni] = __builtin_amdgcn_mfma_f32_16x16x32_bf16(a[mi], b[ni], acc[mi][ni], 0, 0, 0);
    }

#pragma unroll
    for (int mi = 0; mi < MI; ++mi)
#pragma unroll
        for (int ni = 0; ni < NI; ++ni)
#pragma unroll
            for (int r = 0; r < 4; ++r) {
                int m = bm + wm + mi * 16 + lq * 4 + r;
                int nn = bn + wn + ni * 16 + lr;
                float v = acc[mi][ni][r];
                if (do_silu) v = v / (1.f + __expf(-v));
                C[(size_t)m * N + nn] = f2bf(v);
            }
}

// ================= R20: 256x256 GEMM, 1 barrier per K-tile (best known: 44.4us) ==========
#define BAR8 __builtin_amdgcn_s_barrier()
#define SB0  __builtin_amdgcn_sched_barrier(0)
#define VM0 do { asm volatile("s_waitcnt vmcnt(0)" ::: "memory"); } while (0)

template<int GX>
__global__ __launch_bounds__(512, 2)
void gemm8p_k(const us* __restrict__ A, const us* __restrict__ Bt, us* __restrict__ C,
              int N, int K, int Ks, int do_silu, size_t cstride) {
    __shared__ __align__(16) us Alds[2 * 2 * 128 * 64];   // 64 KiB
    __shared__ __align__(16) us Blds[2 * 2 * 128 * 64];   // 64 KiB
    int t = threadIdx.x, lane = t & 63, wave = t >> 6;
    int n0 = blockIdx.x;
    int by = n0 & 15, rest = n0 >> 4;
    int bx = rest % GX, z = rest / GX;
    int bm = by * 256, bn = bx * 256;
    int lr = lane & 15, lq = (lane >> 4) & 3;
    int wm2 = wave >> 2, wn2 = wave & 3;

    const size_t r8 = (size_t)8 * K;
    const us* ga0 = A + (size_t)(bm + wave * 16 + (lane >> 3)) * K
                      + ((lane & 7) ^ (lane >> 3)) * 8 + (size_t)z * Ks;
    const us* ga1 = ga0 + (size_t)128 * K;
    const us* gb0 = Bt + (size_t)(bn + wave * 16 + (lane >> 3)) * K
                       + ((lane & 7) ^ (lane >> 3)) * 8 + (size_t)z * Ks;
    const us* gb1 = gb0 + (size_t)128 * K;
    const int sd = wave * 1024;
    C += (size_t)z * cstride;

    const int sw0 = ((lq ^ (lr & 7)) * 8);
    const int sw1 = (((4 + lq) ^ (lr & 7)) * 8);
    const us* pa00 = &Alds[wm2 * 8192 + lr * 64 + sw0];
    const us* pa01 = &Alds[wm2 * 8192 + lr * 64 + sw1];
    const us* pa10 = pa00 + 16384;
    const us* pa11 = pa01 + 16384;
    const int bo = (wn2 >> 1) * 8192 + (wn2 & 1) * 4096 + lr * 64;
    const us* pb00 = &Blds[bo + sw0];
    const us* pb01 = &Blds[bo + sw1];
    const us* pb10 = pb00 + 16384;
    const us* pb11 = pb01 + 16384;
    us* dA0h0 = &Alds[sd];          us* dA0h1 = &Alds[8192 + sd];
    us* dA1h0 = &Alds[16384 + sd];  us* dA1h1 = &Alds[16384 + 8192 + sd];
    us* dB0h0 = &Blds[sd];          us* dB0h1 = &Blds[8192 + sd];
    us* dB1h0 = &Blds[16384 + sd];  us* dB1h1 = &Blds[16384 + 8192 + sd];

#define STG_A2(d) do { \
    gld_lds16(ga0,      dA##d##h0); gld_lds16(ga0 + r8, dA##d##h0 + 512); \
    gld_lds16(ga1,      dA##d##h1); gld_lds16(ga1 + r8, dA##d##h1 + 512); \
    ga0 += 64; ga1 += 64; } while (0)
#define STG_B2(d) do { \
    gld_lds16(gb0,      dB##d##h0); gld_lds16(gb0 + r8, dB##d##h0 + 512); \
    gld_lds16(gb1,      dB##d##h1); gld_lds16(gb1 + r8, dB##d##h1 + 512); \
    gb0 += 64; gb1 += 64; } while (0)
#define RDA(sl, mf, D) do { \
    aF[sl][0] = *(const short8*)(pa##D##0 + (mf) * 1024); \
    aF[sl][1] = *(const short8*)(pa##D##1 + (mf) * 1024); } while (0)
#define RDB(nf, D) do { \
    bF[nf][0] = *(const short8*)(pb##D##0 + (nf) * 1024); \
    bF[nf][1] = *(const short8*)(pb##D##1 + (nf) * 1024); } while (0)
#define MMROW(mf, sl) do { \
    acc[mf][0] = __builtin_amdgcn_mfma_f32_16x16x32_bf16(aF[sl][0], bF[0][0], acc[mf][0], 0, 0, 0); \
    acc[mf][1] = __builtin_amdgcn_mfma_f32_16x16x32_bf16(aF[sl][0], bF[1][0], acc[mf][1], 0, 0, 0); \
    acc[mf][2] = __builtin_amdgcn_mfma_f32_16x16x32_bf16(aF[sl][0], bF[2][0], acc[mf][2], 0, 0, 0); \
    acc[mf][3] = __builtin_amdgcn_mfma_f32_16x16x32_bf16(aF[sl][0], bF[3][0], acc[mf][3], 0, 0, 0); \
    acc[mf][0] = __builtin_amdgcn_mfma_f32_16x16x32_bf16(aF[sl][1], bF[0][1], acc[mf][0], 0, 0, 0); \
    acc[mf][1] = __builtin_amdgcn_mfma_f32_16x16x32_bf16(aF[sl][1], bF[1][1], acc[mf][1], 0, 0, 0); \
    acc[mf][2] = __builtin_amdgcn_mfma_f32_16x16x32_bf16(aF[sl][1], bF[2][1], acc[mf][2], 0, 0, 0); \
    acc[mf][3] = __builtin_amdgcn_mfma_f32_16x16x32_bf16(aF[sl][1], bF[3][1], acc[mf][3], 0, 0, 0); } while (0)

#define TILE_S(D, E) do { \
    BAR8; \
    RDB(0, D); RDB(1, D); RDB(2, D); RDB(3, D); \
    RDA(0, 0, D); RDA(1, 1, D); RDA(2, 2, D); RDA(3, 3, D); \
    SB0; \
    STG_A2(E); STG_B2(E); \
    SB0; \
    __builtin_amdgcn_s_setprio(1); MMROW(0, 0); MMROW(1, 1); __builtin_amdgcn_s_setprio(0); \
    RDA(0, 4, D); RDA(1, 5, D); SB0; \
    __builtin_amdgcn_s_setprio(1); MMROW(2, 2); MMROW(3, 3); __builtin_amdgcn_s_setprio(0); \
    RDA(2, 6, D); RDA(3, 7, D); SB0; \
    __builtin_amdgcn_s_setprio(1); MMROW(4, 0); MMROW(5, 1); __builtin_amdgcn_s_setprio(0); \
    __builtin_amdgcn_s_setprio(1); MMROW(6, 2); MMROW(7, 3); __builtin_amdgcn_s_setprio(0); \
    VM0; } while (0)
#define TILE_N(D) do { \
    BAR8; \
    RDB(0, D); RDB(1, D); RDB(2, D); RDB(3, D); \
    RDA(0, 0, D); RDA(1, 1, D); RDA(2, 2, D); RDA(3, 3, D); \
    SB0; \
    __builtin_amdgcn_s_setprio(1); MMROW(0, 0); MMROW(1, 1); __builtin_amdgcn_s_setprio(0); \
    RDA(0, 4, D); RDA(1, 5, D); SB0; \
    __builtin_amdgcn_s_setprio(1); MMROW(2, 2); MMROW(3, 3); __builtin_amdgcn_s_setprio(0); \
    RDA(2, 6, D); RDA(3, 7, D); SB0; \
    __builtin_amdgcn_s_setprio(1); MMROW(4, 0); MMROW(5, 1); __builtin_amdgcn_s_setprio(0); \
    __builtin_amdgcn_s_setprio(1); MMROW(6, 2); MMROW(7, 3); __builtin_amdgcn_s_setprio(0); } while (0)

    floatx4 acc[8][4];
#pragma unroll
    for (int mf = 0; mf < 8; ++mf)
#pragma unroll
        for (int nf = 0; nf < 4; ++nf)
            acc[mf][nf] = (floatx4){0.f, 0.f, 0.f, 0.f};

    short8 aF[4][2], bF[4][2];

    STG_B2(0); STG_A2(0);
    VM0;

    const int NP = Ks >> 7;
    for (int i = 0; i < NP - 1; ++i) {
        TILE_S(0, 1);
        TILE_S(1, 0);
    }
    TILE_S(0, 1);
    TILE_N(1);

    int cm = bm + wm2 * 128, cn = bn + wn2 * 64;
#pragma unroll
    for (int mf = 0; mf < 8; ++mf)
#pragma unroll
        for (int nf = 0; nf < 4; ++nf)
#pragma unroll
            for (int r = 0; r < 4; ++r) {
                int m = cm + mf * 16 + lq * 4 + r;
                int nn = cn + nf * 16 + lr;
                float v = acc[mf][nf][r];
                if (do_silu) v = v / (1.f + __expf(-v));
                C[(size_t)m * N + nn] = f2bf(v);
            }
#undef STG_A2
#undef STG_B2
#undef RDA
#undef RDB
#undef MMROW
#undef TILE_S
#undef TILE_N
}

// ================= R22: 128x256 GEMM, BK=32, 48 KiB LDS, CONFLICT-FIXED swizzle ==========
// R21 post-mortem: slot = lq^(row&3) put rows {0,4,8,12} in the same (parity,slot) bank
// bucket -> 4-way conflict (4.19M counted). Fix = legacy R10 mapping: slot = lq^((row>>1)&3)
// -> each (row&1, slot) bucket holds exactly 2 lanes = 2-way = free.
// Deployed on FFN1 only this round: within-run A/B vs gemm8p FFN2 (same 34.4 GFLOP).
template<int GXc>
__global__ __launch_bounds__(512, 2)
void gemm128_k(const us* __restrict__ A, const us* __restrict__ Bt, us* __restrict__ C,
               int N, int K, int Ks, int do_silu, size_t cstride) {
    __shared__ __align__(16) us Al[2][128 * 32];   // 2 x 8 KiB
    __shared__ __align__(16) us Bl[2][256 * 32];   // 2 x 16 KiB
    int t = threadIdx.x, lane = t & 63, wave = t >> 6;
    int n0 = blockIdx.x;
    int by = n0 & 31, rest = n0 >> 5;       // M=4096 -> 32 row-blocks of 128
    int bx = rest % GXc, z = rest / GXc;
    int bm = by * 128, bn = bx * 256;
    int lr = lane & 15, lq = lane >> 4;     // lq in 0..3
    int wm2 = wave >> 2, wn2 = wave & 3;    // 2M x 4N wave grid, per-wave C 64x64

    int srow = lane >> 2;
    int schk = ((lane & 3) ^ ((srow >> 1) & 3)) * 8;   // R22 fix: ^((row>>1)&3)
    const us* ga = A + (size_t)(bm + wave * 16 + srow) * K + schk + (size_t)z * Ks;
    const us* gb = Bt + (size_t)(bn + wave * 32 + srow) * K + schk + (size_t)z * Ks;
    const size_t r16 = (size_t)16 * K;
    us* dA0 = &Al[0][wave * 512];  us* dA1 = &Al[1][wave * 512];
    us* dB0 = &Bl[0][wave * 1024]; us* dB1 = &Bl[1][wave * 1024];
    C += (size_t)z * cstride;

    const int rsw = (lq ^ ((lr >> 1) & 3)) * 8;        // R22 fix: matching involution
    const us* pa0 = &Al[0][(wm2 * 64 + lr) * 32 + rsw];
    const us* pa1 = &Al[1][(wm2 * 64 + lr) * 32 + rsw];
    const us* pb0 = &Bl[0][(wn2 * 64 + lr) * 32 + rsw];
    const us* pb1 = &Bl[1][(wn2 * 64 + lr) * 32 + rsw];

#define STG(d) do { \
    gld_lds16(ga, dA##d); \
    gld_lds16(gb, dB##d); gld_lds16(gb + r16, dB##d + 512); \
    ga += 32; gb += 32; } while (0)
#define RD(D) do { \
    aF[0] = *(const short8*)(pa##D);        aF[1] = *(const short8*)(pa##D + 512); \
    aF[2] = *(const short8*)(pa##D + 1024); aF[3] = *(const short8*)(pa##D + 1536); \
    bF[0] = *(const short8*)(pb##D);        bF[1] = *(const short8*)(pb##D + 512); \
    bF[2] = *(const short8*)(pb##D + 1024); bF[3] = *(const short8*)(pb##D + 1536); } while (0)
#define MM16 do { \
    _Pragma("unroll") \
    for (int mf = 0; mf < 4; ++mf) { \
        acc[mf][0] = __builtin_amdgcn_mfma_f32_16x16x32_bf16(aF[mf], bF[0], acc[mf][0], 0, 0, 0); \
        acc[mf][1] = __builtin_amdgcn_mfma_f32_16x16x32_bf16(aF[mf], bF[1], acc[mf][1], 0, 0, 0); \
        acc[mf][2] = __builtin_amdgcn_mfma_f32_16x16x32_bf16(aF[mf], bF[2], acc[mf][2], 0, 0, 0); \
        acc[mf][3] = __builtin_amdgcn_mfma_f32_16x16x32_bf16(aF[mf], bF[3], acc[mf][3], 0, 0, 0); \
    } } while (0)
#define TILE_S(D, E) do { \
    BAR8; \
    RD(D); \
    SB0; STG(E); SB0; \
    __builtin_amdgcn_s_setprio(1); MM16; __builtin_amdgcn_s_setprio(0); \
    VM0; } while (0)
#define TILE_N(D) do { \
    BAR8; \
    RD(D); \
    __builtin_amdgcn_s_setprio(1); MM16; __builtin_amdgcn_s_setprio(0); } while (0)

    floatx4 acc[4][4];
#pragma unroll
    for (int mf = 0; mf < 4; ++mf)
#pragma unroll
        for (int nf = 0; nf < 4; ++nf)
            acc[mf][nf] = (floatx4){0.f, 0.f, 0.f, 0.f};

    short8 aF[4], bF[4];

    STG(0);
    VM0;

    const int NT = Ks >> 5;                 // K-tiles of 32; Ks=1024 -> 32
    for (int i = 0; i < NT / 2 - 1; ++i) {
        TILE_S(0, 1);
        TILE_S(1, 0);
    }
    TILE_S(0, 1);
    TILE_N(1);

    int cm = bm + wm2 * 64, cn = bn + wn2 * 64;
#pragma unroll
    for (int mf = 0; mf < 4; ++mf)
#pragma unroll
        for (int nf = 0; nf < 4; ++nf)
#pragma unroll
            for (int r = 0; r < 4; ++r) {
                int m = cm + mf * 16 + lq * 4 + r;
                int nn = cn + nf * 16 + lr;
                float v = acc[mf][nf][r];
                if (do_silu) v = v / (1.f + __expf(-v));
                C[(size_t)m * N + nn] = f2bf(v);
            }
#undef STG
#undef RD
#undef MM16
#undef TILE_S
#undef TILE_N
}

// ================= Flash attention: 512-thread blocks, 2 q-tiles sharing one K/V pass ======
#define PSTR 72

template<bool DIAG>
__device__ __forceinline__ void flash_tile_nm(
    const short8& qf0, const short8& qf1,
    floatx4* oa, float* lrw,
    const us* Ks, const us* Vts, us* Ps, const short8& ones,
    int lr, int lq, int sub)
{
    floatx4 s[4];
#pragma unroll
    for (int n = 0; n < 4; ++n) {
        int R = n * 16 + lr;
        short8 kf0 = *(const short8*)&Ks[R * 64 + ((lq ^ (R & 7)) << 3)];
        short8 kf1 = *(const short8*)&Ks[R * 64 + (((lq + 4) ^ (R & 7)) << 3)];
        floatx4 z = (floatx4){0.f, 0.f, 0.f, 0.f};
        z = __builtin_amdgcn_mfma_f32_16x16x32_bf16(qf0, kf0, z, 0, 0, 0);
        s[n] = __builtin_amdgcn_mfma_f32_16x16x32_bf16(qf1, kf1, z, 0, 0, 0);
    }
    if (DIAG) {
#pragma unroll
        for (int n = 0; n < 4; ++n)
#pragma unroll
            for (int r = 0; r < 4; ++r)
                if ((n * 16 + lr) > (sub * 16 + lq * 4 + r)) s[n][r] = -1e30f;  // exp2 -> 0
    }
#pragma unroll
    for (int r = 0; r < 4; ++r) {
        union { unsigned int u[2]; short4v v; } pk;
        pk.u[0] = pk_trunc(__builtin_amdgcn_exp2f(s[0][r]), __builtin_amdgcn_exp2f(s[1][r]));
        pk.u[1] = pk_trunc(__builtin_amdgcn_exp2f(s[2][r]), __builtin_amdgcn_exp2f(s[3][r]));
        *(short4v*)&Ps[(lq * 4 + r) * PSTR + lr * 4] = pk.v;
    }
    asm volatile("s_waitcnt lgkmcnt(0)" ::: "memory");
    __builtin_amdgcn_sched_barrier(0);

    floatx4 zs = (floatx4){0.f, 0.f, 0.f, 0.f};
    __builtin_amdgcn_s_setprio(1);
#pragma unroll
    for (int kx = 0; kx < 2; ++kx) {
        short8 pf = *(const short8*)&Ps[lr * PSTR + kx * 32 + lq * 8];
        zs = __builtin_amdgcn_mfma_f32_16x16x32_bf16(pf, ones, zs, 0, 0, 0);
#pragma unroll
        for (int nd = 0; nd < 4; ++nd) {
            int R = nd * 16 + lr;
            short8 vf = *(const short8*)&Vts[R * 64 + ((((kx << 2) | lq) ^ (R & 7)) << 3)];
            oa[nd] = __builtin_amdgcn_mfma_f32_16x16x32_bf16(pf, vf, oa[nd], 0, 0, 0);
        }
    }
    __builtin_amdgcn_s_setprio(0);
#pragma unroll
    for (int r = 0; r < 4; ++r) lrw[r] += zs[r];
}

__global__ __launch_bounds__(512, 6) void attn_k(const us* __restrict__ q,
                                                 const us* __restrict__ kg,
                                                 const us* __restrict__ vt,
                                                 us* __restrict__ o,
                                                 us* __restrict__ Po,
                                                 float* __restrict__ Pl) {
    __shared__ __align__(16) us Ks[2][64 * 64];
    __shared__ __align__(16) us Vts[2][64 * 64];
    __shared__ __align__(16) us Ps[8 * 16 * PSTR];
    int j = blockIdx.x;
    int part = (j >= 16);
    int P = part ? (j - 8) : j;
    int qtA = 2 * P, qtB = 2 * P + 1;
    int k0 = part ? 16 : 0;
    int k1 = part ? qtB : (qtB < 15 ? qtB : 15);
    bool fin = (!part) && (P < 8);
    int bh = blockIdx.y;
    int b = bh >> 4, h = bh & 15;
    size_t base = (size_t)b * TSEQ;
    const us* vth = vt + ((size_t)b * DMODEL + h * 64) * TSEQ;
    int t = threadIdx.x, lane = t & 63, wave = t >> 6;   // wave 0..7
    int sub = wave & 3, grp = wave >> 2;                 // strip index, q-tile group
    int myqt = grp ? qtB : qtA;
    int lr = lane & 15, lq = lane >> 4;

    const float SC = 0.18033688011112042f;  // (1/8)*log2(e)
    int qrow = myqt * 64 + sub * 16 + lr;
    short8 qf0 = *(const short8*)&q[(base + qrow) * QKVS + h * 64 + lq * 8];
    short8 qf1 = *(const short8*)&q[(base + qrow) * QKVS + h * 64 + 32 + lq * 8];
#pragma unroll
    for (int e = 0; e < 8; ++e) {
        qf0[e] = (short)f2bf(bf2f((us)qf0[e]) * SC);
        qf1[e] = (short)f2bf(bf2f((us)qf1[e]) * SC);
    }
    short8 ones;
#pragma unroll
    for (int e = 0; e < 8; ++e) ones[e] = (short)0x3F80;  // bf16 1.0

    us* Psw = &Ps[wave * 16 * PSTR];

    floatx4 oa[4];
    float lrw[4] = {0.f, 0.f, 0.f, 0.f};
#pragma unroll
    for (int i = 0; i < 4; ++i) oa[i] = (floatx4){0.f, 0.f, 0.f, 0.f};

    int rsub = lane >> 3;
    int cda = ((lane & 7) ^ rsub) * 8;
    const us* gK = kg + (base + wave * 8 + rsub) * QKVS + h * 64 + cda;
    const us* gV = vth + (size_t)(wave * 8 + rsub) * TSEQ + cda;

    gld_lds16(gK + (size_t)(k0 * 64) * QKVS, &Ks[0][(wave * 8) * 64]);
    gld_lds16(gV + k0 * 64, &Vts[0][(wave * 8) * 64]);

    for (int kt = k0; kt <= k1; ++kt) {
        __syncthreads();
        int cur = (kt - k0) & 1, nxt = cur ^ 1;
        if (kt < k1) {
            gld_lds16(gK + (size_t)((kt + 1) * 64) * QKVS, &Ks[nxt][(wave * 8) * 64]);
            gld_lds16(gV + (kt + 1) * 64, &Vts[nxt][(wave * 8) * 64]);
        }
        if (kt <= myqt) {
            if (kt == myqt)
                flash_tile_nm<true>(qf0, qf1, oa, lrw, Ks[cur], Vts[cur], Psw, ones, lr, lq, sub);
            else
                flash_tile_nm<false>(qf0, qf1, oa, lrw, Ks[cur], Vts[cur], Psw, ones, lr, lq, sub);
        }
    }

    if (fin) {
#pragma unroll
        for (int nd = 0; nd < 4; ++nd)
#pragma unroll
            for (int r = 0; r < 4; ++r) {
                int tok = myqt * 64 + sub * 16 + lq * 4 + r;
                o[(base + tok) * DMODEL + h * 64 + nd * 16 + lr] = f2bf(oa[nd][r] / lrw[r]);
            }
    } else {
#pragma unroll
        for (int nd = 0; nd < 4; ++nd)
#pragma unroll
            for (int r = 0; r < 4; ++r) {
                int tok = myqt * 64 + sub * 16 + lq * 4 + r;
                size_t pb = ((size_t)(part * BATCH + b) * 1024 + (tok - 1024)) * 1024;
                Po[pb + h * 64 + nd * 16 + lr] = f2bf(oa[nd][r]);
            }
        if (lr == 0) {
#pragma unroll
            for (int r = 0; r < 4; ++r) {
                int tok = myqt * 64 + sub * 16 + lq * 4 + r;
                Pl[((part * BATCH + b) * NHEADS + h) * TSEQ + tok] = lrw[r];
            }
        }
    }
}

__global__ void merge_k(const us* __restrict__ Po, const float* __restrict__ Pl,
                        us* __restrict__ ab) {
    int row = blockIdx.x;            // 0..2047
    int b = row >> 10, tloc = row & 1023;
    int t = 1024 + tloc;
    int t4 = threadIdx.x * 4;
    int h = t4 >> 6;
    float l0 = Pl[((0 * BATCH + b) * NHEADS + h) * TSEQ + t];
    float l1 = Pl[((1 * BATCH + b) * NHEADS + h) * TSEQ + t];
    float inv = 1.f / (l0 + l1);
    size_t o0 = ((size_t)(0 * BATCH + b) * 1024 + tloc) * 1024 + t4;
    size_t o1 = ((size_t)(1 * BATCH + b) * 1024 + tloc) * 1024 + t4;
    us p0[4], p1[4], ol[4];
    *(uint2*)p0 = *(const uint2*)&Po[o0];
    *(uint2*)p1 = *(const uint2*)&Po[o1];
    for (int e = 0; e < 4; ++e)
        ol[e] = f2bf((bf2f(p0[e]) + bf2f(p1[e])) * inv);
    *(uint2*)&ab[((size_t)b * TSEQ + t) * DMODEL + t4] = *(uint2*)ol;
}

// ---------------- launch ----------------
extern "C" void kernel_launch(void* const* d_in, const int* in_sizes, int n_in,
                              void* d_out, int out_size, void* d_ws, size_t ws_size,
                              hipStream_t stream) {
    const float* x      = (const float*)d_in[0];
    const float* w_pre  = (const float*)d_in[1];
    const float* wq     = (const float*)d_in[2];
    const float* wk     = (const float*)d_in[3];
    const float* wv     = (const float*)d_in[4];
    const float* wo     = (const float*)d_in[5];
    const float* w_attn = (const float*)d_in[6];
    const float* w1     = (const float*)d_in[7];
    const float* w2     = (const float*)d_in[8];
    const float* w_ffn  = (const float*)d_in[9];

    char* ws = (char*)d_ws;
    const size_t MB = 1024 * 1024;
    us* hb    = (us*)(ws + 0);
    us* qkvb  = (us*)(ws + 8 * MB);
    us* ab    = (us*)(ws + 32 * MB);
    us* vtb   = (us*)(ws + 40 * MB);
    us* ob0   = (us*)(ws + 40 * MB);
    us* ob1   = (us*)(ws + 48 * MB);
    us* Pob   = (us*)(ws + 48 * MB);
    us* yb    = (us*)(ws + 0);        // in-place over hb (row-local safe)
    us* wqkvt = (us*)(ws + 56 * MB);  // 6 MB
    us* wot   = (us*)(ws + 62 * MB);  // 2 MB
    us* w1t   = (us*)(ws + 64 * MB);  // 8 MB
    us* w2t   = (us*)(ws + 72 * MB);  // 8 MB
    float* Pl = (float*)(ws + 80 * MB); // 1 MB
    us* midb  = (us*)(ws + 8 * MB);   // 32 MB FFN mid (qkvb+ab dead)
    us* fb0   = (us*)(ws + 40 * MB);  // FFN2 split-K=4 partials, 8 MB stride, [40,72)
    const size_t FB_STR = (8 * MB) / 2;

    dim3 tb(32, 8);
    // 6 transposes + pre-norm in one launch (12288 tiles + 4096 rows)
    prologue_k<<<dim3(16384), tb, 0, stream>>>(
        wq, wk, wv, wo, w1, w2, x, w_pre, wqkvt, wot, w1t, w2t, hb);

    // fused QKV: R20 gemm8p (best known), 16x12 = 192 blocks
    gemm8p_k<12><<<dim3(192), 512, 0, stream>>>(
        hb, wqkvt, qkvb, QKVS, DMODEL, DMODEL, 0, 0);

    vtrans_k<<<dim3(DMODEL / 32, TSEQ / 32, BATCH), tb, 0, stream>>>(qkvb + 2048, vtb, QKVS);

    attn_k<<<dim3(24, BATCH * NHEADS), 512, 0, stream>>>(qkvb, qkvb + 1024, vtb, ab, Pob, Pl);
    merge_k<<<dim3(BATCH * 1024), 256, 0, stream>>>(Pob, Pl, ab);

    // O-proj: legacy 2-phase, GX=8, split-K=2 -> 512 blocks (short K; small op)
    gemm_dbuf_k<128, 8, true><<<dim3(512), 256, 0, stream>>>(
        ab, wot, ob0, BT, DMODEL, DMODEL, 0, DMODEL / 2, (size_t)BT * DMODEL);
    resnorm_k<<<BT, 256, 0, stream>>>(hb, ob0, ob1, w_attn, yb, 0);

    // FFN1: R22 A/B arm — conflict-fixed gemm128, 32x16 = 512 blocks (2/CU), fused silu
    gemm128_k<16><<<dim3(512), 512, 0, stream>>>(
        yb, w1t, midb, FFDIM, DMODEL, DMODEL, 1, 0);
    // FFN2: R20 gemm8p control arm — split-K=4, 256 blocks (1/CU), same 34.4 GFLOP
    gemm8p_k<4><<<dim3(256), 512, 0, stream>>>(
        midb, w2t, fb0, DMODEL, FFDIM, FFDIM / 4, 0, FB_STR);
    resnorm4_k<<<BT, 256, 0, stream>>>(yb, fb0, FB_STR, w_ffn, (float*)d_out);
}

// Round 11
// 308.735 us; speedup vs baseline: 1.1283x; 1.0442x over previous
//
#include <hip/hip_runtime.h>
#include <cstdint>
#include <cstddef>

#define TSEQ   2048
#define BATCH  2
#define BT     4096      // BATCH*TSEQ
#define DMODEL 1024
#define NHEADS 16
#define HDIM   64
#define FFDIM  4096
#define QKVS   3072      // row stride of fused qkv buffer

typedef __attribute__((ext_vector_type(8))) short short8;    // 8 bf16 = 4 VGPRs
typedef __attribute__((ext_vector_type(4))) short short4v;   // 8B of bf16
typedef __attribute__((ext_vector_type(4))) float floatx4;   // MFMA acc
typedef unsigned short us;

__device__ __forceinline__ float bf2f(us u) {
    union { unsigned int i; float f; } v; v.i = ((unsigned int)u) << 16; return v.f;
}
__device__ __forceinline__ us f2bf(float f) {
    union { float f; unsigned int i; } v; v.f = f;
    unsigned int r = v.i + 0x7fffu + ((v.i >> 16) & 1u);
    return (us)(r >> 16);
}
__device__ __forceinline__ unsigned int fbits(float f) {
    union { float f; unsigned int u; } v; v.f = f; return v.u;
}
// pack two f32 -> two bf16 (truncating; P in [0,1] so <=1 ULP down). lo -> low half.
__device__ __forceinline__ unsigned int pk_trunc(float lo, float hi) {
    return (fbits(hi) & 0xffff0000u) | (fbits(lo) >> 16);
}

// async global->LDS, 16B per lane. LDS dest = wave-uniform base + lane*16.
__device__ __forceinline__ void gld_lds16(const us* g, us* l) {
    __builtin_amdgcn_global_load_lds(
        (const __attribute__((address_space(1))) uint32_t*)(const void*)g,
        (__attribute__((address_space(3))) uint32_t*)(void*)l, 16, 0, 0);
}

// ============ R23 prologue: 64x64 transpose tiles + pre-norm, fully-coalesced writes =====
// Block (64,8) = 512 threads. blocks [0,1024): wq/wk/wv/wo (256 tiles each);
// [1024,2048): w1; [2048,3072): w2; [3072,5120): rmsnorm, 2 rows per block.
// Transpose: reads 256B/wave-row (64 f32), writes 128B/wave-row (64 bf16) — R19's 32-wide
// tiles wrote 64B rows (half-coalesced) on 48 MB of stores.
__global__ void prologue_k(const float* __restrict__ wq, const float* __restrict__ wk,
                           const float* __restrict__ wv, const float* __restrict__ wo,
                           const float* __restrict__ w1, const float* __restrict__ w2,
                           const float* __restrict__ x,  const float* __restrict__ w_pre,
                           us* __restrict__ wqkvt, us* __restrict__ wot,
                           us* __restrict__ w1t, us* __restrict__ w2t,
                           us* __restrict__ hb) {
    __shared__ us tile[64][65];
    __shared__ float red[8];
    int tb = blockIdx.x;
    int tx = threadIdx.x, ty = threadIdx.y;  // (64,8)
    if (tb >= 3072) {                         // ---- rmsnorm: 2 rows per block ----
        int tid = ty * 64 + tx;               // 0..511
        int half = tid >> 8;                  // 0/1 -> which row
        int t = tid & 255;                    // 0..255 within row
        int row = (tb - 3072) * 2 + half;
        float4 xv = *(const float4*)&x[(size_t)row * DMODEL + t * 4];
        float f[4] = {xv.x, xv.y, xv.z, xv.w};
        float ss = 0.f;
        for (int e = 0; e < 4; ++e) ss += f[e] * f[e];
        for (int m = 1; m < 64; m <<= 1) ss += __shfl_xor(ss, m);
        int wave = tid >> 6;                  // 0..7; waves 0-3 = row0, 4-7 = row1
        if ((tid & 63) == 0) red[wave] = ss;
        __syncthreads();
        int rb = half * 4;
        float tot = red[rb] + red[rb + 1] + red[rb + 2] + red[rb + 3];
        float sc = rsqrtf(tot * (1.f / DMODEL) + 1e-6f);
        float4 wv4 = *(const float4*)&w_pre[t * 4];
        float wf[4] = {wv4.x, wv4.y, wv4.z, wv4.w};
        us ol[4];
        for (int e = 0; e < 4; ++e) ol[e] = f2bf(f[e] * sc * wf[e]);
        *(uint2*)&hb[(size_t)row * DMODEL + t * 4] = *(uint2*)ol;
        return;
    }
    const float* in; us* out; int K, N, nt, kt;
    if (tb < 1024) {                          // four 1024x1024 weights, 256 tiles each
        int w = tb >> 8, u = tb & 255;
        in = (w == 0) ? wq : (w == 1) ? wk : (w == 2) ? wv : wo;
        out = (w < 3) ? (wqkvt + (size_t)w * 1024 * 1024) : wot;
        K = 1024; N = 1024; nt = (u & 15) * 64; kt = (u >> 4) * 64;
    } else if (tb < 2048) {                   // w1: [1024 K][4096 N]
        int u = tb - 1024;
        in = w1; out = w1t; K = 1024; N = 4096; nt = (u & 63) * 64; kt = (u >> 6) * 64;
    } else {                                  // w2: [4096 K][1024 N]
        int u = tb - 2048;
        in = w2; out = w2t; K = 4096; N = 1024; nt = (u & 15) * 64; kt = (u >> 4) * 64;
    }
    // read: 64 f32/wave-row coalesced; store bf16 into LDS
    for (int i = 0; i < 8; ++i)
        tile[ty + 8 * i][tx] = f2bf(in[(size_t)(kt + ty + 8 * i) * N + nt + tx]);
    __syncthreads();
    // write: out[n][K], 64 consecutive bf16 (128B) per wave-row
    for (int j = 0; j < 8; ++j)
        out[(size_t)(nt + ty + 8 * j) * K + kt + tx] = tile[tx][ty + 8 * j];
}

// ---------------- bf16 transpose: V (strided rows) -> Vt [B*D][T], key-permuted ---------
// Within each 64-key block, key k is stored at col sigma(k) = ((k&15)<<2)|((k&63)>>4).
// Matches the packed P storage in attn (storage col c holds key pi(c)=(c&3)*16+(c>>2);
// pi = sigma^-1), so the PV contraction sees identical key order on both operands.
__global__ void vtrans_k(const us* __restrict__ in, us* __restrict__ out, int istride) {
    __shared__ us tile[32][33];
    int b = blockIdx.z;
    int ct = blockIdx.x * 32;   // D tile
    int rt = blockIdx.y * 32;   // T tile
    int tx = threadIdx.x, ty = threadIdx.y; // (32,8)
    for (int i = 0; i < 4; ++i)
        tile[ty + 8 * i][tx] = in[((size_t)b * TSEQ + rt + ty + 8 * i) * istride + ct + tx];
    __syncthreads();
    int tt = rt + tx;
    int ts = (tt & ~63) | ((tt & 15) << 2) | ((tt & 63) >> 4);
    for (int i = 0; i < 4; ++i)
        out[((size_t)b * DMODEL + ct + ty + 8 * i) * TSEQ + ts] = tile[tx][ty + 8 * i];
}

// ---------------- Residual + RMSNorm: out = rmsnorm(a + b [+ b2]) * w ----------------
__global__ void resnorm_k(const us* a, const us* b,
                          const us* b2,
                          const float* w,
                          void* outp, int out_f32) {
    int row = blockIdx.x, t = threadIdx.x;
    us al[4], bl[4], cl[4];
    *(uint2*)al = *(const uint2*)&a[(size_t)row * DMODEL + t * 4];
    *(uint2*)bl = *(const uint2*)&b[(size_t)row * DMODEL + t * 4];
    if (b2) *(uint2*)cl = *(const uint2*)&b2[(size_t)row * DMODEL + t * 4];
    float f[4];
    float ss = 0.f;
    for (int e = 0; e < 4; ++e) {
        f[e] = bf2f(al[e]) + bf2f(bl[e]);
        if (b2) f[e] += bf2f(cl[e]);
        ss += f[e] * f[e];
    }
    for (int m = 1; m < 64; m <<= 1) ss += __shfl_xor(ss, m);
    __shared__ float red[4];
    if ((t & 63) == 0) red[t >> 6] = ss;
    __syncthreads();
    float tot = red[0] + red[1] + red[2] + red[3];
    float sc = rsqrtf(tot * (1.f / DMODEL) + 1e-6f);
    float4 wv = *(const float4*)&w[t * 4];
    float wf[4] = {wv.x, wv.y, wv.z, wv.w};
    if (out_f32) {
        float4 ov;
        ov.x = f[0] * sc * wf[0]; ov.y = f[1] * sc * wf[1];
        ov.z = f[2] * sc * wf[2]; ov.w = f[3] * sc * wf[3];
        *(float4*)&((float*)outp)[(size_t)row * DMODEL + t * 4] = ov;
    } else {
        us ol[4];
        for (int e = 0; e < 4; ++e) ol[e] = f2bf(f[e] * sc * wf[e]);
        *(uint2*)&((us*)outp)[(size_t)row * DMODEL + t * 4] = *(uint2*)ol;
    }
}

// ---------------- Residual + RMSNorm over 4 split-K partials (f32 out) ----------------
__global__ void resnorm4_k(const us* __restrict__ a, const us* __restrict__ p,
                           size_t pstride, const float* __restrict__ w,
                           float* __restrict__ out) {
    int row = blockIdx.x, t = threadIdx.x;
    size_t off = (size_t)row * DMODEL + t * 4;
    us al[4], pl[4][4];
    *(uint2*)al = *(const uint2*)&a[off];
#pragma unroll
    for (int z = 0; z < 4; ++z)
        *(uint2*)pl[z] = *(const uint2*)&p[off + z * pstride];
    float f[4];
    float ss = 0.f;
#pragma unroll
    for (int e = 0; e < 4; ++e) {
        f[e] = bf2f(al[e]) + bf2f(pl[0][e]) + bf2f(pl[1][e]) + bf2f(pl[2][e]) + bf2f(pl[3][e]);
        ss += f[e] * f[e];
    }
    for (int m = 1; m < 64; m <<= 1) ss += __shfl_xor(ss, m);
    __shared__ float red[4];
    if ((t & 63) == 0) red[t >> 6] = ss;
    __syncthreads();
    float tot = red[0] + red[1] + red[2] + red[3];
    float sc = rsqrtf(tot * (1.f / DMODEL) + 1e-6f);
    float4 wv = *(const float4*)&w[t * 4];
    float4 ov;
    ov.x = f[0] * sc * wv.x; ov.y = f[1] * sc * wv.y;
    ov.z = f[2] * sc * wv.z; ov.w = f[3] * sc * wv.w;
    *(float4*)&out[off] = ov;
}

// ---------------- legacy 128-tile 2-phase GEMM (kept for O-proj: short K, small) -------
template<int BN, int GX, bool SWZ>
__global__ __launch_bounds__(256, (BN == 256) ? 2 : 4)
void gemm_dbuf_k(const us* __restrict__ A,
                 const us* __restrict__ Bt,
                 us* __restrict__ C,
                 int M, int N, int K, int do_silu,
                 int Ks, size_t cstride) {
    constexpr int MI = 4, NI = BN / 32;
    constexpr int BDMA = BN / 64;
    __shared__ __align__(16) us As[2][128 * 32];
    __shared__ __align__(16) us Bs[2][BN * 32];
    int t = threadIdx.x;
    int n0 = blockIdx.x;
    int bx, by, z;
    if (SWZ) {
        int c = n0 & 7, bb = n0 >> 3;
        bx = bb % GX;
        int g = bb / GX;
        int yz = c + 8 * g;
        by = yz & 31; z = yz >> 5;
    } else {
        bx = n0 % GX;
        int bb = n0 / GX;
        by = bb & 31; z = bb >> 5;
    }
    int bm = by * 128, bn = bx * BN;
    int lane = t & 63, wave = t >> 6;
    int wm = (wave & 1) * 64, wn = (wave >> 1) * (BN / 2);
    int lr = lane & 15, lq = lane >> 4;

    int sr = lane >> 2;
    int sc = (((lane & 3) ^ ((lane >> 3) & 3)) * 8);
    const us* gA = A + (size_t)(bm + wave * 32 + sr) * K + sc + (size_t)z * Ks;
    const us* gB = Bt + (size_t)(bn + wave * (BN / 4) + sr) * K + sc + (size_t)z * Ks;
    const int aoff = (wave * 32) * 32;
    const int boff = (wave * (BN / 4)) * 32;
    C += (size_t)z * cstride;

    floatx4 acc[MI][NI];
#pragma unroll
    for (int mi = 0; mi < MI; ++mi)
#pragma unroll
        for (int ni = 0; ni < NI; ++ni)
            acc[mi][ni] = (floatx4){0.f, 0.f, 0.f, 0.f};

#pragma unroll
    for (int i = 0; i < 2; ++i)
        gld_lds16(gA + (size_t)(16 * i) * K, &As[0][aoff + i * 16 * 32]);
#pragma unroll
    for (int i = 0; i < BDMA; ++i)
        gld_lds16(gB + (size_t)(16 * i) * K, &Bs[0][boff + i * 16 * 32]);

    int aslot = ((lq ^ ((lr >> 1) & 3)) << 3);

    int nk = Ks >> 5;
    for (int kk = 0; kk < nk; ++kk) {
        __syncthreads();
        int cur = kk & 1, nxt = cur ^ 1;
        if (kk + 1 < nk) {
            size_t off = (size_t)(kk + 1) * 32;
#pragma unroll
            for (int i = 0; i < 2; ++i)
                gld_lds16(gA + (size_t)(16 * i) * K + off, &As[nxt][aoff + i * 16 * 32]);
#pragma unroll
            for (int i = 0; i < BDMA; ++i)
                gld_lds16(gB + (size_t)(16 * i) * K + off, &Bs[nxt][boff + i * 16 * 32]);
        }
        short8 a[MI], b[NI];
#pragma unroll
        for (int mi = 0; mi < MI; ++mi)
            a[mi] = *(const short8*)&As[cur][(wm + mi * 16 + lr) * 32 + aslot];
#pragma unroll
        for (int ni = 0; ni < NI; ++ni)
            b[ni] = *(const short8*)&Bs[cur][(wn + ni * 16 + lr) * 32 + aslot];
#pragma unroll
        for (int mi = 0; mi < MI; ++mi)
#pragma unroll
            for (int ni = 0; ni < NI; ++ni)
                acc[mi][ni] = __builtin_amdgcn_mfma_f32_16x16x32_bf16(a[mi], b[ni], acc[mi][ni], 0, 0, 0);
    }

#pragma unroll
    for (int mi = 0; mi < MI; ++mi)
#pragma unroll
        for (int ni = 0; ni < NI; ++ni)
#pragma unroll
            for (int r = 0; r < 4; ++r) {
                int m = bm + wm + mi * 16 + lq * 4 + r;
                int nn = bn + wn + ni * 16 + lr;
                float v = acc[mi][ni][r];
                if (do_silu) v = v / (1.f + __expf(-v));
                C[(size_t)m * N + nn] = f2bf(v);
            }
}

// ================= R20: 256x256 GEMM, 1 barrier per K-tile (best known: 44.4us) ==========
// R22 A/B closed the book: conflict-free 128x256 @2 blocks/CU = 57us > this @1 block/CU.
// GEMM structure frozen here per pre-commitment; ~3.2x over MFMA floor is the plain-HIP
// structural ceiling for these K=1024 shapes in this session.
#define BAR8 __builtin_amdgcn_s_barrier()
#define SB0  __builtin_amdgcn_sched_barrier(0)
#define VM0 do { asm volatile("s_waitcnt vmcnt(0)" ::: "memory"); } while (0)

template<int GX>
__global__ __launch_bounds__(512, 2)
void gemm8p_k(const us* __restrict__ A, const us* __restrict__ Bt, us* __restrict__ C,
              int N, int K, int Ks, int do_silu, size_t cstride) {
    __shared__ __align__(16) us Alds[2 * 2 * 128 * 64];   // 64 KiB
    __shared__ __align__(16) us Blds[2 * 2 * 128 * 64];   // 64 KiB
    int t = threadIdx.x, lane = t & 63, wave = t >> 6;
    int n0 = blockIdx.x;
    int by = n0 & 15, rest = n0 >> 4;
    int bx = rest % GX, z = rest / GX;
    int bm = by * 256, bn = bx * 256;
    int lr = lane & 15, lq = (lane >> 4) & 3;
    int wm2 = wave >> 2, wn2 = wave & 3;

    const size_t r8 = (size_t)8 * K;
    const us* ga0 = A + (size_t)(bm + wave * 16 + (lane >> 3)) * K
                      + ((lane & 7) ^ (lane >> 3)) * 8 + (size_t)z * Ks;
    const us* ga1 = ga0 + (size_t)128 * K;
    const us* gb0 = Bt + (size_t)(bn + wave * 16 + (lane >> 3)) * K
                       + ((lane & 7) ^ (lane >> 3)) * 8 + (size_t)z * Ks;
    const us* gb1 = gb0 + (size_t)128 * K;
    const int sd = wave * 1024;
    C += (size_t)z * cstride;

    const int sw0 = ((lq ^ (lr & 7)) * 8);
    const int sw1 = (((4 + lq) ^ (lr & 7)) * 8);
    const us* pa00 = &Alds[wm2 * 8192 + lr * 64 + sw0];
    const us* pa01 = &Alds[wm2 * 8192 + lr * 64 + sw1];
    const us* pa10 = pa00 + 16384;
    const us* pa11 = pa01 + 16384;
    const int bo = (wn2 >> 1) * 8192 + (wn2 & 1) * 4096 + lr * 64;
    const us* pb00 = &Blds[bo + sw0];
    const us* pb01 = &Blds[bo + sw1];
    const us* pb10 = pb00 + 16384;
    const us* pb11 = pb01 + 16384;
    us* dA0h0 = &Alds[sd];          us* dA0h1 = &Alds[8192 + sd];
    us* dA1h0 = &Alds[16384 + sd];  us* dA1h1 = &Alds[16384 + 8192 + sd];
    us* dB0h0 = &Blds[sd];          us* dB0h1 = &Blds[8192 + sd];
    us* dB1h0 = &Blds[16384 + sd];  us* dB1h1 = &Blds[16384 + 8192 + sd];

#define STG_A2(d) do { \
    gld_lds16(ga0,      dA##d##h0); gld_lds16(ga0 + r8, dA##d##h0 + 512); \
    gld_lds16(ga1,      dA##d##h1); gld_lds16(ga1 + r8, dA##d##h1 + 512); \
    ga0 += 64; ga1 += 64; } while (0)
#define STG_B2(d) do { \
    gld_lds16(gb0,      dB##d##h0); gld_lds16(gb0 + r8, dB##d##h0 + 512); \
    gld_lds16(gb1,      dB##d##h1); gld_lds16(gb1 + r8, dB##d##h1 + 512); \
    gb0 += 64; gb1 += 64; } while (0)
#define RDA(sl, mf, D) do { \
    aF[sl][0] = *(const short8*)(pa##D##0 + (mf) * 1024); \
    aF[sl][1] = *(const short8*)(pa##D##1 + (mf) * 1024); } while (0)
#define RDB(nf, D) do { \
    bF[nf][0] = *(const short8*)(pb##D##0 + (nf) * 1024); \
    bF[nf][1] = *(const short8*)(pb##D##1 + (nf) * 1024); } while (0)
#define MMROW(mf, sl) do { \
    acc[mf][0] = __builtin_amdgcn_mfma_f32_16x16x32_bf16(aF[sl][0], bF[0][0], acc[mf][0], 0, 0, 0); \
    acc[mf][1] = __builtin_amdgcn_mfma_f32_16x16x32_bf16(aF[sl][0], bF[1][0], acc[mf][1], 0, 0, 0); \
    acc[mf][2] = __builtin_amdgcn_mfma_f32_16x16x32_bf16(aF[sl][0], bF[2][0], acc[mf][2], 0, 0, 0); \
    acc[mf][3] = __builtin_amdgcn_mfma_f32_16x16x32_bf16(aF[sl][0], bF[3][0], acc[mf][3], 0, 0, 0); \
    acc[mf][0] = __builtin_amdgcn_mfma_f32_16x16x32_bf16(aF[sl][1], bF[0][1], acc[mf][0], 0, 0, 0); \
    acc[mf][1] = __builtin_amdgcn_mfma_f32_16x16x32_bf16(aF[sl][1], bF[1][1], acc[mf][1], 0, 0, 0); \
    acc[mf][2] = __builtin_amdgcn_mfma_f32_16x16x32_bf16(aF[sl][1], bF[2][1], acc[mf][2], 0, 0, 0); \
    acc[mf][3] = __builtin_amdgcn_mfma_f32_16x16x32_bf16(aF[sl][1], bF[3][1], acc[mf][3], 0, 0, 0); } while (0)

#define TILE_S(D, E) do { \
    BAR8; \
    RDB(0, D); RDB(1, D); RDB(2, D); RDB(3, D); \
    RDA(0, 0, D); RDA(1, 1, D); RDA(2, 2, D); RDA(3, 3, D); \
    SB0; \
    STG_A2(E); STG_B2(E); \
    SB0; \
    __builtin_amdgcn_s_setprio(1); MMROW(0, 0); MMROW(1, 1); __builtin_amdgcn_s_setprio(0); \
    RDA(0, 4, D); RDA(1, 5, D); SB0; \
    __builtin_amdgcn_s_setprio(1); MMROW(2, 2); MMROW(3, 3); __builtin_amdgcn_s_setprio(0); \
    RDA(2, 6, D); RDA(3, 7, D); SB0; \
    __builtin_amdgcn_s_setprio(1); MMROW(4, 0); MMROW(5, 1); __builtin_amdgcn_s_setprio(0); \
    __builtin_amdgcn_s_setprio(1); MMROW(6, 2); MMROW(7, 3); __builtin_amdgcn_s_setprio(0); \
    VM0; } while (0)
#define TILE_N(D) do { \
    BAR8; \
    RDB(0, D); RDB(1, D); RDB(2, D); RDB(3, D); \
    RDA(0, 0, D); RDA(1, 1, D); RDA(2, 2, D); RDA(3, 3, D); \
    SB0; \
    __builtin_amdgcn_s_setprio(1); MMROW(0, 0); MMROW(1, 1); __builtin_amdgcn_s_setprio(0); \
    RDA(0, 4, D); RDA(1, 5, D); SB0; \
    __builtin_amdgcn_s_setprio(1); MMROW(2, 2); MMROW(3, 3); __builtin_amdgcn_s_setprio(0); \
    RDA(2, 6, D); RDA(3, 7, D); SB0; \
    __builtin_amdgcn_s_setprio(1); MMROW(4, 0); MMROW(5, 1); __builtin_amdgcn_s_setprio(0); \
    __builtin_amdgcn_s_setprio(1); MMROW(6, 2); MMROW(7, 3); __builtin_amdgcn_s_setprio(0); } while (0)

    floatx4 acc[8][4];
#pragma unroll
    for (int mf = 0; mf < 8; ++mf)
#pragma unroll
        for (int nf = 0; nf < 4; ++nf)
            acc[mf][nf] = (floatx4){0.f, 0.f, 0.f, 0.f};

    short8 aF[4][2], bF[4][2];

    STG_B2(0); STG_A2(0);
    VM0;

    const int NP = Ks >> 7;
    for (int i = 0; i < NP - 1; ++i) {
        TILE_S(0, 1);
        TILE_S(1, 0);
    }
    TILE_S(0, 1);
    TILE_N(1);

    int cm = bm + wm2 * 128, cn = bn + wn2 * 64;
#pragma unroll
    for (int mf = 0; mf < 8; ++mf)
#pragma unroll
        for (int nf = 0; nf < 4; ++nf)
#pragma unroll
            for (int r = 0; r < 4; ++r) {
                int m = cm + mf * 16 + lq * 4 + r;
                int nn = cn + nf * 16 + lr;
                float v = acc[mf][nf][r];
                if (do_silu) v = v / (1.f + __expf(-v));
                C[(size_t)m * N + nn] = f2bf(v);
            }
#undef STG_A2
#undef STG_B2
#undef RDA
#undef RDB
#undef MMROW
#undef TILE_S
#undef TILE_N
}

// ================= Flash attention: 512-thread blocks, 2 q-tiles sharing one K/V pass ======
#define PSTR 72

template<bool DIAG>
__device__ __forceinline__ void flash_tile_nm(
    const short8& qf0, const short8& qf1,
    floatx4* oa, float* lrw,
    const us* Ks, const us* Vts, us* Ps, const short8& ones,
    int lr, int lq, int sub)
{
    floatx4 s[4];
#pragma unroll
    for (int n = 0; n < 4; ++n) {
        int R = n * 16 + lr;
        short8 kf0 = *(const short8*)&Ks[R * 64 + ((lq ^ (R & 7)) << 3)];
        short8 kf1 = *(const short8*)&Ks[R * 64 + (((lq + 4) ^ (R & 7)) << 3)];
        floatx4 z = (floatx4){0.f, 0.f, 0.f, 0.f};
        z = __builtin_amdgcn_mfma_f32_16x16x32_bf16(qf0, kf0, z, 0, 0, 0);
        s[n] = __builtin_amdgcn_mfma_f32_16x16x32_bf16(qf1, kf1, z, 0, 0, 0);
    }
    if (DIAG) {
#pragma unroll
        for (int n = 0; n < 4; ++n)
#pragma unroll
            for (int r = 0; r < 4; ++r)
                if ((n * 16 + lr) > (sub * 16 + lq * 4 + r)) s[n][r] = -1e30f;  // exp2 -> 0
    }
#pragma unroll
    for (int r = 0; r < 4; ++r) {
        union { unsigned int u[2]; short4v v; } pk;
        pk.u[0] = pk_trunc(__builtin_amdgcn_exp2f(s[0][r]), __builtin_amdgcn_exp2f(s[1][r]));
        pk.u[1] = pk_trunc(__builtin_amdgcn_exp2f(s[2][r]), __builtin_amdgcn_exp2f(s[3][r]));
        *(short4v*)&Ps[(lq * 4 + r) * PSTR + lr * 4] = pk.v;
    }
    asm volatile("s_waitcnt lgkmcnt(0)" ::: "memory");
    __builtin_amdgcn_sched_barrier(0);

    floatx4 zs = (floatx4){0.f, 0.f, 0.f, 0.f};
    __builtin_amdgcn_s_setprio(1);
#pragma unroll
    for (int kx = 0; kx < 2; ++kx) {
        short8 pf = *(const short8*)&Ps[lr * PSTR + kx * 32 + lq * 8];
        zs = __builtin_amdgcn_mfma_f32_16x16x32_bf16(pf, ones, zs, 0, 0, 0);
#pragma unroll
        for (int nd = 0; nd < 4; ++nd) {
            int R = nd * 16 + lr;
            short8 vf = *(const short8*)&Vts[R * 64 + ((((kx << 2) | lq) ^ (R & 7)) << 3)];
            oa[nd] = __builtin_amdgcn_mfma_f32_16x16x32_bf16(pf, vf, oa[nd], 0, 0, 0);
        }
    }
    __builtin_amdgcn_s_setprio(0);
#pragma unroll
    for (int r = 0; r < 4; ++r) lrw[r] += zs[r];
}

__global__ __launch_bounds__(512, 6) void attn_k(const us* __restrict__ q,
                                                 const us* __restrict__ kg,
                                                 const us* __restrict__ vt,
                                                 us* __restrict__ o,
                                                 us* __restrict__ Po,
                                                 float* __restrict__ Pl) {
    __shared__ __align__(16) us Ks[2][64 * 64];
    __shared__ __align__(16) us Vts[2][64 * 64];
    __shared__ __align__(16) us Ps[8 * 16 * PSTR];
    int j = blockIdx.x;
    int part = (j >= 16);
    int P = part ? (j - 8) : j;
    int qtA = 2 * P, qtB = 2 * P + 1;
    int k0 = part ? 16 : 0;
    int k1 = part ? qtB : (qtB < 15 ? qtB : 15);
    bool fin = (!part) && (P < 8);
    int bh = blockIdx.y;
    int b = bh >> 4, h = bh & 15;
    size_t base = (size_t)b * TSEQ;
    const us* vth = vt + ((size_t)b * DMODEL + h * 64) * TSEQ;
    int t = threadIdx.x, lane = t & 63, wave = t >> 6;   // wave 0..7
    int sub = wave & 3, grp = wave >> 2;                 // strip index, q-tile group
    int myqt = grp ? qtB : qtA;
    int lr = lane & 15, lq = lane >> 4;

    const float SC = 0.18033688011112042f;  // (1/8)*log2(e)
    int qrow = myqt * 64 + sub * 16 + lr;
    short8 qf0 = *(const short8*)&q[(base + qrow) * QKVS + h * 64 + lq * 8];
    short8 qf1 = *(const short8*)&q[(base + qrow) * QKVS + h * 64 + 32 + lq * 8];
#pragma unroll
    for (int e = 0; e < 8; ++e) {
        qf0[e] = (short)f2bf(bf2f((us)qf0[e]) * SC);
        qf1[e] = (short)f2bf(bf2f((us)qf1[e]) * SC);
    }
    short8 ones;
#pragma unroll
    for (int e = 0; e < 8; ++e) ones[e] = (short)0x3F80;  // bf16 1.0

    us* Psw = &Ps[wave * 16 * PSTR];

    floatx4 oa[4];
    float lrw[4] = {0.f, 0.f, 0.f, 0.f};
#pragma unroll
    for (int i = 0; i < 4; ++i) oa[i] = (floatx4){0.f, 0.f, 0.f, 0.f};

    int rsub = lane >> 3;
    int cda = ((lane & 7) ^ rsub) * 8;
    const us* gK = kg + (base + wave * 8 + rsub) * QKVS + h * 64 + cda;
    const us* gV = vth + (size_t)(wave * 8 + rsub) * TSEQ + cda;

    gld_lds16(gK + (size_t)(k0 * 64) * QKVS, &Ks[0][(wave * 8) * 64]);
    gld_lds16(gV + k0 * 64, &Vts[0][(wave * 8) * 64]);

    for (int kt = k0; kt <= k1; ++kt) {
        __syncthreads();
        int cur = (kt - k0) & 1, nxt = cur ^ 1;
        if (kt < k1) {
            gld_lds16(gK + (size_t)((kt + 1) * 64) * QKVS, &Ks[nxt][(wave * 8) * 64]);
            gld_lds16(gV + (kt + 1) * 64, &Vts[nxt][(wave * 8) * 64]);
        }
        if (kt <= myqt) {
            if (kt == myqt)
                flash_tile_nm<true>(qf0, qf1, oa, lrw, Ks[cur], Vts[cur], Psw, ones, lr, lq, sub);
            else
                flash_tile_nm<false>(qf0, qf1, oa, lrw, Ks[cur], Vts[cur], Psw, ones, lr, lq, sub);
        }
    }

    if (fin) {
#pragma unroll
        for (int nd = 0; nd < 4; ++nd)
#pragma unroll
            for (int r = 0; r < 4; ++r) {
                int tok = myqt * 64 + sub * 16 + lq * 4 + r;
                o[(base + tok) * DMODEL + h * 64 + nd * 16 + lr] = f2bf(oa[nd][r] / lrw[r]);
            }
    } else {
#pragma unroll
        for (int nd = 0; nd < 4; ++nd)
#pragma unroll
            for (int r = 0; r < 4; ++r) {
                int tok = myqt * 64 + sub * 16 + lq * 4 + r;
                size_t pb = ((size_t)(part * BATCH + b) * 1024 + (tok - 1024)) * 1024;
                Po[pb + h * 64 + nd * 16 + lr] = f2bf(oa[nd][r]);
            }
        if (lr == 0) {
#pragma unroll
            for (int r = 0; r < 4; ++r) {
                int tok = myqt * 64 + sub * 16 + lq * 4 + r;
                Pl[((part * BATCH + b) * NHEADS + h) * TSEQ + tok] = lrw[r];
            }
        }
    }
}

__global__ void merge_k(const us* __restrict__ Po, const float* __restrict__ Pl,
                        us* __restrict__ ab) {
    int row = blockIdx.x;            // 0..2047
    int b = row >> 10, tloc = row & 1023;
    int t = 1024 + tloc;
    int t4 = threadIdx.x * 4;
    int h = t4 >> 6;
    float l0 = Pl[((0 * BATCH + b) * NHEADS + h) * TSEQ + t];
    float l1 = Pl[((1 * BATCH + b) * NHEADS + h) * TSEQ + t];
    float inv = 1.f / (l0 + l1);
    size_t o0 = ((size_t)(0 * BATCH + b) * 1024 + tloc) * 1024 + t4;
    size_t o1 = ((size_t)(1 * BATCH + b) * 1024 + tloc) * 1024 + t4;
    us p0[4], p1[4], ol[4];
    *(uint2*)p0 = *(const uint2*)&Po[o0];
    *(uint2*)p1 = *(const uint2*)&Po[o1];
    for (int e = 0; e < 4; ++e)
        ol[e] = f2bf((bf2f(p0[e]) + bf2f(p1[e])) * inv);
    *(uint2*)&ab[((size_t)b * TSEQ + t) * DMODEL + t4] = *(uint2*)ol;
}

// ---------------- launch ----------------
extern "C" void kernel_launch(void* const* d_in, const int* in_sizes, int n_in,
                              void* d_out, int out_size, void* d_ws, size_t ws_size,
                              hipStream_t stream) {
    const float* x      = (const float*)d_in[0];
    const float* w_pre  = (const float*)d_in[1];
    const float* wq     = (const float*)d_in[2];
    const float* wk     = (const float*)d_in[3];
    const float* wv     = (const float*)d_in[4];
    const float* wo     = (const float*)d_in[5];
    const float* w_attn = (const float*)d_in[6];
    const float* w1     = (const float*)d_in[7];
    const float* w2     = (const float*)d_in[8];
    const float* w_ffn  = (const float*)d_in[9];

    char* ws = (char*)d_ws;
    const size_t MB = 1024 * 1024;
    us* hb    = (us*)(ws + 0);
    us* qkvb  = (us*)(ws + 8 * MB);
    us* ab    = (us*)(ws + 32 * MB);
    us* vtb   = (us*)(ws + 40 * MB);
    us* ob0   = (us*)(ws + 40 * MB);
    us* ob1   = (us*)(ws + 48 * MB);
    us* Pob   = (us*)(ws + 48 * MB);
    us* yb    = (us*)(ws + 0);        // in-place over hb (row-local safe)
    us* wqkvt = (us*)(ws + 56 * MB);  // 6 MB
    us* wot   = (us*)(ws + 62 * MB);  // 2 MB
    us* w1t   = (us*)(ws + 64 * MB);  // 8 MB
    us* w2t   = (us*)(ws + 72 * MB);  // 8 MB
    float* Pl = (float*)(ws + 80 * MB); // 1 MB
    us* midb  = (us*)(ws + 8 * MB);   // 32 MB FFN mid (qkvb+ab dead)
    us* fb0   = (us*)(ws + 40 * MB);  // FFN2 split-K=4 partials, 8 MB stride, [40,72)
    const size_t FB_STR = (8 * MB) / 2;

    // R23: 64x64-tile transposes + pre-norm, one launch, 5120 blocks of (64,8)
    prologue_k<<<dim3(5120), dim3(64, 8), 0, stream>>>(
        wq, wk, wv, wo, w1, w2, x, w_pre, wqkvt, wot, w1t, w2t, hb);

    // fused QKV: R20 gemm8p (best known), 16x12 = 192 blocks
    gemm8p_k<12><<<dim3(192), 512, 0, stream>>>(
        hb, wqkvt, qkvb, QKVS, DMODEL, DMODEL, 0, 0);

    vtrans_k<<<dim3(DMODEL / 32, TSEQ / 32, BATCH), dim3(32, 8), 0, stream>>>(
        qkvb + 2048, vtb, QKVS);

    attn_k<<<dim3(24, BATCH * NHEADS), 512, 0, stream>>>(qkvb, qkvb + 1024, vtb, ab, Pob, Pl);
    merge_k<<<dim3(BATCH * 1024), 256, 0, stream>>>(Pob, Pl, ab);

    // O-proj: legacy 2-phase, GX=8, split-K=2 -> 512 blocks (short K; small op)
    gemm_dbuf_k<128, 8, true><<<dim3(512), 256, 0, stream>>>(
        ab, wot, ob0, BT, DMODEL, DMODEL, 0, DMODEL / 2, (size_t)BT * DMODEL);
    resnorm_k<<<BT, 256, 0, stream>>>(hb, ob0, ob1, w_attn, yb, 0);

    // FFN1: REVERTED to R20 gemm8p<16> (R22 A/B: small-tile 2/CU = 57us > this 44.4us)
    gemm8p_k<16><<<dim3(256), 512, 0, stream>>>(
        yb, w1t, midb, FFDIM, DMODEL, DMODEL, 1, 0);
    // FFN2: R20 gemm8p, split-K=4, 256 blocks
    gemm8p_k<4><<<dim3(256), 512, 0, stream>>>(
        midb, w2t, fb0, DMODEL, FFDIM, FFDIM / 4, 0, FB_STR);
    resnorm4_k<<<BT, 256, 0, stream>>>(yb, fb0, FB_STR, w_ffn, (float*)d_out);
}